// Round 10
// baseline (316.780 us; speedup 1.0000x reference)
//
#include <hip/hip_runtime.h>
#include <stdint.h>
#include <math.h>

#define NB 4
#define NU 1024
#define NS 256
#define NF 16
#define ND 256
#define NEGV -1000000000.0f
#define VBIT (1 << 14)
#define AGENT __HIP_MEMORY_SCOPE_AGENT
#define SPINCAP (1 << 20)
#define NGRP 64            // blocks per batch
#define SPB 4              // servers per block

// propA[par + bs]: bits0-9 argu | bits10-13 fid | bit14 valid | bits15-20 epoch | maxv<<32
// propB[par + bs]: low32 = -log(sum) bits | high32 = epoch
// ctrl: [256],[257] det[2]

// ---------- detect connect dtype (int32 / float32 / byte), parallel ----------
__global__ __launch_bounds__(256) void k_detect(const uint8_t* __restrict__ conn,
                                                unsigned* __restrict__ det) {
  int i = blockIdx.x * 256 + threadIdx.x;
  uchar4 v = ((const uchar4*)conn)[i];
  bool c0 = v.x != 0;
  bool c123 = (v.y | v.z | v.w) != 0;
  unsigned long long m0 = __ballot(c0);
  unsigned long long m1 = __ballot(c123);
  if ((threadIdx.x & 63) == 0) {
    if (m0) atomicOr(&det[0], 1u);
    if (m1) atomicOr(&det[1], 1u);
  }
}

// ---------- transpose connect -> bitmask [b][s][u/32], coalesced via LDS ----------
__global__ __launch_bounds__(256) void k_transpose(const uint8_t* __restrict__ conn,
                                                   const unsigned* __restrict__ det,
                                                   uint32_t* __restrict__ connT) {
  unsigned d0 = det[0], d1 = det[1];
  int f = (d1 == 0) ? 0 : ((d0 == 0) ? 1 : 2);
  int blk = blockIdx.x;          // b*32 + ug ; 128 blocks
  int b = blk >> 5, ug = blk & 31;
  int u0 = ug * 32;
  int t = threadIdx.x;
  __shared__ uint8_t sm[32][260];
#pragma unroll 4
  for (int r = 0; r < 32; ++r) {
    int e = (b * NU + u0 + r) * NS + t;
    bool nz;
    if (f == 0)      nz = ((const int*)conn)[e] != 0;
    else if (f == 1) nz = ((const float*)conn)[e] != 0.0f;
    else             nz = conn[e] != 0;
    sm[r][t] = nz ? 1 : 0;
  }
  __syncthreads();
  uint32_t word = 0;
#pragma unroll
  for (int j = 0; j < 32; ++j) word |= (uint32_t)sm[j][t] << j;
  connT[(b * NS + t) * 32 + ug] = word;
}

// ---------- WS_K[d][c] = sum_e W_k[d][e] * W_state[e][c] ----------
__global__ __launch_bounds__(256) void k_weights(const float* __restrict__ W_state,
                                                 const float* __restrict__ W_k,
                                                 float* __restrict__ WS_K) {
  int d = threadIdx.x;
  const float4* wk4 = (const float4*)(W_k + d * ND);
  const float4* ws4 = (const float4*)W_state;
  float a0 = 0, a1 = 0, a2 = 0, a3 = 0;
  for (int e4 = 0; e4 < ND / 4; ++e4) {
    float4 k4 = wk4[e4];
    float4 w0 = ws4[e4 * 4 + 0];
    a0 += k4.x * w0.x; a1 += k4.x * w0.y; a2 += k4.x * w0.z; a3 += k4.x * w0.w;
    float4 w1 = ws4[e4 * 4 + 1];
    a0 += k4.y * w1.x; a1 += k4.y * w1.y; a2 += k4.y * w1.z; a3 += k4.y * w1.w;
    float4 w2 = ws4[e4 * 4 + 2];
    a0 += k4.z * w2.x; a1 += k4.z * w2.y; a2 += k4.z * w2.z; a3 += k4.z * w2.w;
    float4 w3 = ws4[e4 * 4 + 3];
    a0 += k4.w * w3.x; a1 += k4.w * w3.y; a2 += k4.w * w3.z; a3 += k4.w * w3.w;
  }
  ((float4*)WS_K)[d] = make_float4(a0, a1, a2, a3);
}

// ---------- f32 GEMM, 128x64 tile, double-buffered LDS ----------
// Per-element accumulation order identical to prior rounds (single acc, k ascending,
// acc += a*b statements) -> bit-identical C -> trajectory preserved.
__global__ __launch_bounds__(256) void k_gemm128(
    const float* __restrict__ A, const float* __restrict__ Bm, float* __restrict__ C,
    int K, int lda, int ldb, int ldc, long sA, long sB, long sC,
    const float* __restrict__ biasA, float alpha) {
  int z = blockIdx.z;
  A += (size_t)z * sA; Bm += (size_t)z * sB; C += (size_t)z * sC;
  int m0 = blockIdx.y * 128, n0 = blockIdx.x * 64;
  int t = threadIdx.x;
  int tx = t & 15, ty = t >> 4;     // tx: n-quad, ty: m-oct
  __shared__ float As[2][16][132];
  __shared__ float Bs[2][16][68];
  float acc[8][4];
#pragma unroll
  for (int i = 0; i < 8; i++)
#pragma unroll
    for (int j = 0; j < 4; j++) acc[i][j] = 0.f;
  int ar = t >> 1;                  // A row 0..127
  int akq = (t & 1) * 8;            // A k offset 0/8
  int br = t >> 2;                  // B row 0..63
  int bkq = (t & 3) * 4;            // B k offset

  {
    float4 a0 = *(const float4*)(A + (size_t)(m0 + ar) * lda + akq);
    float4 a1 = *(const float4*)(A + (size_t)(m0 + ar) * lda + akq + 4);
    if (biasA) {
      const float* bp = biasA + akq;
      a0.x += bp[0]; a0.y += bp[1]; a0.z += bp[2]; a0.w += bp[3];
      a1.x += bp[4]; a1.y += bp[5]; a1.z += bp[6]; a1.w += bp[7];
    }
    As[0][akq + 0][ar] = a0.x; As[0][akq + 1][ar] = a0.y;
    As[0][akq + 2][ar] = a0.z; As[0][akq + 3][ar] = a0.w;
    As[0][akq + 4][ar] = a1.x; As[0][akq + 5][ar] = a1.y;
    As[0][akq + 6][ar] = a1.z; As[0][akq + 7][ar] = a1.w;
    float4 bv = *(const float4*)(Bm + (size_t)(n0 + br) * ldb + bkq);
    Bs[0][bkq + 0][br] = bv.x; Bs[0][bkq + 1][br] = bv.y;
    Bs[0][bkq + 2][br] = bv.z; Bs[0][bkq + 3][br] = bv.w;
  }
  __syncthreads();

  int nt = K >> 4;
  for (int ti = 0; ti < nt; ++ti) {
    int buf = ti & 1;
    float4 a0n, a1n, bvn;
    bool more = (ti + 1 < nt);
    if (more) {
      int k0 = (ti + 1) << 4;
      a0n = *(const float4*)(A + (size_t)(m0 + ar) * lda + k0 + akq);
      a1n = *(const float4*)(A + (size_t)(m0 + ar) * lda + k0 + akq + 4);
      if (biasA) {
        const float* bp = biasA + k0 + akq;
        a0n.x += bp[0]; a0n.y += bp[1]; a0n.z += bp[2]; a0n.w += bp[3];
        a1n.x += bp[4]; a1n.y += bp[5]; a1n.z += bp[6]; a1n.w += bp[7];
      }
      bvn = *(const float4*)(Bm + (size_t)(n0 + br) * ldb + k0 + bkq);
    }
#pragma unroll
    for (int k = 0; k < 16; ++k) {
      float4 aA = *(const float4*)&As[buf][k][ty * 8];
      float4 aB = *(const float4*)&As[buf][k][ty * 8 + 4];
      float4 bb = *(const float4*)&Bs[buf][k][tx * 4];
      float am[8] = {aA.x, aA.y, aA.z, aA.w, aB.x, aB.y, aB.z, aB.w};
      float bn[4] = {bb.x, bb.y, bb.z, bb.w};
#pragma unroll
      for (int i = 0; i < 8; ++i)
#pragma unroll
        for (int j = 0; j < 4; ++j) acc[i][j] += am[i] * bn[j];
    }
    if (more) {
      __syncthreads();
      int nb = buf ^ 1;
      As[nb][akq + 0][ar] = a0n.x; As[nb][akq + 1][ar] = a0n.y;
      As[nb][akq + 2][ar] = a0n.z; As[nb][akq + 3][ar] = a0n.w;
      As[nb][akq + 4][ar] = a1n.x; As[nb][akq + 5][ar] = a1n.y;
      As[nb][akq + 6][ar] = a1n.z; As[nb][akq + 7][ar] = a1n.w;
      Bs[nb][bkq + 0][br] = bvn.x; Bs[nb][bkq + 1][br] = bvn.y;
      Bs[nb][bkq + 2][br] = bvn.z; Bs[nb][bkq + 3][br] = bvn.w;
      __syncthreads();
    }
  }
#pragma unroll
  for (int i = 0; i < 8; ++i) {
    float4 o = make_float4(acc[i][0] * alpha, acc[i][1] * alpha,
                           acc[i][2] * alpha, acc[i][3] * alpha);
    *(float4*)(C + (size_t)(m0 + ty * 8 + i) * ldc + n0 + tx * 4) = o;
  }
}

// ---------- qc[bu][c] = inv_sqrt_d * sum_d q[bu][d] * WS_K[d][c], wave per row ----------
__global__ __launch_bounds__(256) void k_qc(const float* __restrict__ q,
                                            const float* __restrict__ WS_K,
                                            float* __restrict__ qc) {
  int row = blockIdx.x * 4 + (threadIdx.x >> 6);
  int ln = threadIdx.x & 63;
  const float* qr = q + (size_t)row * ND;
  float a0 = 0, a1 = 0, a2 = 0, a3 = 0;
  for (int d = ln; d < ND; d += 64) {
    float qv = qr[d];
    float4 w = ((const float4*)WS_K)[d];
    a0 += qv * w.x; a1 += qv * w.y; a2 += qv * w.z; a3 += qv * w.w;
  }
  for (int o = 32; o; o >>= 1) {
    a0 += __shfl_xor(a0, o); a1 += __shfl_xor(a1, o);
    a2 += __shfl_xor(a2, o); a3 += __shfl_xor(a3, o);
  }
  if (ln == 0)
    ((float4*)qc)[row] = make_float4(a0 * 0.0625f, a1 * 0.0625f, a2 * 0.0625f, a3 * 0.0625f);
}

// ---------- the 32-step allocator: 4 servers/block, 64 blocks/batch,
//            epoch-tagged proposals (store IS the barrier signal) ----------
__global__ __launch_bounds__(256) void k_steps4(
    const float* __restrict__ L0T, const float* __restrict__ qc,
    const float* __restrict__ users, const float* __restrict__ servers,
    const uint32_t* __restrict__ connT, const float* __restrict__ fd_onehot,
    const float* __restrict__ W_us, const float* __restrict__ fd_alpha,
    const float* __restrict__ fd_beta, const float* __restrict__ score_bias,
    unsigned long long* __restrict__ propA, unsigned long long* __restrict__ propB,
    uint32_t* __restrict__ allocW, float* __restrict__ capF, float* __restrict__ out) {
  __shared__ float redM[SPB][256];
  __shared__ int redA[SPB][256];
  __shared__ unsigned keyEnc[NU];
  __shared__ unsigned srvMin[NU];
  __shared__ float lsum[NU];
  __shared__ uint32_t fdSh[NU];
  __shared__ float4 capS4[SPB];
  __shared__ float4 crS4[SPB];
  __shared__ float4 minv4[SPB];
  __shared__ int fidS[SPB];
  __shared__ float bM[SPB];
  __shared__ int bA[SPB];
  __shared__ float wredL[4];
  __shared__ int sAny;

  const int blk = blockIdx.x;
  const int b = blk >> 6;         // batch
  const int g = blk & 63;         // group (servers g*4 .. g*4+3)
  const int tid = threadIdx.x;
  const int wv = tid >> 6, ln64 = tid & 63;
  const int sg = tid >> 6;        // server group (0..3), 64 lanes each
  const int bs0 = b * NS + g * SPB;

  const float a_ = fd_alpha[0], be_ = fd_beta[0];
  const float t0 = tanhf(be_), t1 = tanhf(a_ + be_);
  const float sb = score_bias[0];
  const float w0 = W_us[0], w1 = W_us[1], w2 = W_us[2];

  if (tid < SPB) {
    int srow = bs0 + tid;
    int f = 0;
    for (int ff = 0; ff < NF; ++ff)
      if (fd_onehot[srow * NF + ff] > 0.5f) { f = ff; break; }
    fidS[tid] = f;
    float4 ic = make_float4(servers[srow * 8 + 3], servers[srow * 8 + 4],
                            servers[srow * 8 + 5], servers[srow * 8 + 6]);
    capS4[tid] = ic;
    minv4[tid] = make_float4(fmaxf(ic.x, 1e-6f), fmaxf(ic.y, 1e-6f),
                             fmaxf(ic.z, 1e-6f), fmaxf(ic.w, 1e-6f));
  }

  float qc0[4], qc1[4], qc2[4], qc3[4], nax[4], nay[4], nbx[4], nby[4];
  float L0r[SPB][4];
  uint32_t upk[4] = {0, 0, 0, 0};   // bits 0-15 fdmask, bits 16-17 rc
  float usv[4];
  float logpv[4] = {0, 0, 0, 0};
  uint32_t cb = 0, ab = 0;          // bit (s*4+it): conn / alloc for own servers
#pragma unroll
  for (int it = 0; it < 4; ++it) {
    int u = it * 256 + tid, gu = b * NU + u;
    float4 q4 = *(const float4*)(qc + gu * 4);
    qc0[it] = q4.x; qc1[it] = q4.y; qc2[it] = q4.z; qc3[it] = q4.w;
    float2 nA = *(const float2*)(users + gu * 8 + 2);
    float2 nB2 = *(const float2*)(users + gu * 8 + 4);
    nax[it] = nA.x; nay[it] = nA.y; nbx[it] = nB2.x; nby[it] = nB2.y;
    usv[it] = w1;
  }
#pragma unroll
  for (int s = 0; s < SPB; ++s)
#pragma unroll
    for (int it = 0; it < 4; ++it) {
      L0r[s][it] = L0T[(size_t)(bs0 + s) * NU + it * 256 + tid];
      uint32_t word = connT[(bs0 + s) * 32 + it * 8 + (tid >> 5)];
      cb |= ((word >> (tid & 31)) & 1u) << (s * 4 + it);
    }
  for (int i = tid; i < NU; i += 256) {
    keyEnc[i] = 0u; srvMin[i] = 0xFFFFFFFFu; lsum[i] = 0.f; fdSh[i] = 0u;
  }
  __syncthreads();

  for (int step = 0; step < 32; ++step) {
    unsigned e = (unsigned)(step + 1);
    if (tid < SPB) {
      float4 c = capS4[tid];
      float4 mv = minv4[tid];
      crS4[tid] = make_float4(c.x / mv.x, c.y / mv.y, c.z / mv.z, c.w / mv.w);
    }
    __syncthreads();

    // ---- phase A ----
    float cand[SPB][4];
#pragma unroll
    for (int s = 0; s < SPB; ++s) {
      float4 c = capS4[s];
      float4 cr = crS4[s];
      int fid = fidS[s];
      float m = NEGV; int a = 0x7fffffff;
#pragma unroll
      for (int it = 0; it < 4; ++it) {
        int u = it * 256 + tid;
        bool el = ((cb >> (s * 4 + it)) & 1u) && !((ab >> (s * 4 + it)) & 1u) &&
                  ((upk[it] & 0x30000u) != 0x30000u) &&
                  c.x >= nax[it] && c.y >= nay[it] && c.z >= nbx[it] && c.w >= nby[it];
        float tt = ((upk[it] >> fid) & 1u) ? t0 : t1;
        float lg = L0r[s][it] + qc0[it] * cr.x + qc1[it] * cr.y + qc2[it] * cr.z +
                   qc3[it] * cr.w + sb + tt + usv[it];
        float cv = el ? lg : NEGV;
        cand[s][it] = cv;
        if (cv > m || (cv == m && u < a)) { m = cv; a = u; }
      }
      redM[s][tid] = m; redA[s][tid] = a;
    }
    __syncthreads();
    {
      int ln = ln64;
      float m = redM[sg][ln * 4]; int a = redA[sg][ln * 4];
#pragma unroll
      for (int j = 1; j < 4; ++j) {
        float v = redM[sg][ln * 4 + j]; int aa = redA[sg][ln * 4 + j];
        if (v > m || (v == m && aa < a)) { m = v; a = aa; }
      }
      for (int o = 32; o; o >>= 1) {
        float ov = __shfl_xor(m, o); int oa = __shfl_xor(a, o);
        if (ov > m || (ov == m && oa < a)) { m = ov; a = oa; }
      }
      if (ln == 0) { bM[sg] = m; bA[sg] = a; }
    }
    __syncthreads();
#pragma unroll
    for (int s = 0; s < SPB; ++s) {
      float mv = bM[s];
      redM[s][tid] = expf(cand[s][0] - mv) + expf(cand[s][1] - mv) +
                     expf(cand[s][2] - mv) + expf(cand[s][3] - mv);
    }
    __syncthreads();
    {
      int ln = ln64;
      float ps = redM[sg][ln * 4];
#pragma unroll
      for (int j = 1; j < 4; ++j) ps += redM[sg][ln * 4 + j];
      for (int o = 32; o; o >>= 1) ps += __shfl_xor(ps, o);
      if (ln == 0) {
        float maxv = bM[sg]; int argu = bA[sg];
        unsigned validb = (maxv > -1e8f) ? VBIT : 0;
        unsigned pinfo = (unsigned)argu | ((unsigned)fidS[sg] << 10) | validb | (e << 15);
        unsigned long long A = (unsigned long long)pinfo |
                               ((unsigned long long)__float_as_uint(maxv) << 32);
        unsigned long long Bv = (unsigned long long)__float_as_uint(-logf(ps)) |
                                ((unsigned long long)e << 32);
        int par = (step & 1) * (NB * NS);
        __hip_atomic_store(&propA[par + bs0 + sg], A, __ATOMIC_RELAXED, AGENT);
        __hip_atomic_store(&propB[par + bs0 + sg], Bv, __ATOMIC_RELAXED, AGENT);
      }
    }
    // no separate barrier: the epoch-tagged proposal store IS the signal

    // ---- phase B: poll all 256 proposals of the batch; resolve winners ----
    {
      int par = (step & 1) * (NB * NS) + b * NS;
      unsigned long long A;
      {
        int iters = 0;
        for (;;) {
          A = __hip_atomic_load(&propA[par + tid], __ATOMIC_RELAXED, AGENT);
          if ((((unsigned)A >> 15) & 63u) == e) break;
          __builtin_amdgcn_s_sleep(1);
          if (++iters > SPINCAP) break;
        }
      }
      unsigned pi = (unsigned)A;
      if (tid == 0) sAny = 0;
      __syncthreads();
      unsigned long long mm = __ballot((pi & VBIT) != 0);
      if (mm && (tid & 63) == 0) atomicOr(&sAny, 1);
      __syncthreads();
      if (sAny == 0) break;                   // batch frozen forever
      unsigned encv = 0;
      int pu = pi & 1023;
      if (pi & VBIT) {
        unsigned vb = (unsigned)(A >> 32);
        encv = (vb & 0x80000000u) ? ~vb : (vb | 0x80000000u);
        atomicMax(&keyEnc[pu], encv);
        unsigned long long Bv;
        int iters = 0;
        for (;;) {
          Bv = __hip_atomic_load(&propB[par + tid], __ATOMIC_RELAXED, AGENT);
          if ((unsigned)(Bv >> 32) == e) break;
          __builtin_amdgcn_s_sleep(1);
          if (++iters > SPINCAP) break;
        }
        atomicAdd(&lsum[pu], __uint_as_float((unsigned)Bv));
        atomicOr(&fdSh[pu], 1u << ((pi >> 10) & 15));
      }
      __syncthreads();
      if ((pi & VBIT) && keyEnc[pu] == encv)
        atomicMin(&srvMin[pu], (unsigned)tid);
      __syncthreads();
#pragma unroll
      for (int it = 0; it < 4; ++it) {
        int u = it * 256 + tid;
        unsigned ke = keyEnc[u];
        if (ke) {
          unsigned win = srvMin[u];
          logpv[it] += lsum[u];
          uint32_t fda = fdSh[u];
          keyEnc[u] = 0u; srvMin[u] = 0xFFFFFFFFu; lsum[u] = 0.f; fdSh[u] = 0u;
          uint32_t pk = upk[it];
          int r = (int)((pk >> 16) & 3) + 1;
          upk[it] = ((pk | fda) & 0xFFFFu) | ((uint32_t)r << 16);
          float rf = (float)r;
          usv[it] = w0 * (rf / 3.0f) + w1 * (fmaxf(3.0f - rf, 0.f) / 3.0f) +
                    ((r == 2) ? w2 : 0.f);
          if ((int)(win >> 2) == g) {
            int sl = win & 3;
            ab |= 1u << (sl * 4 + it);
            float4 c = capS4[sl];           // unique (server,step) winner -> no race
            capS4[sl] = make_float4(fmaxf(c.x - nax[it], 0.f), fmaxf(c.y - nay[it], 0.f),
                                    fmaxf(c.z - nbx[it], 0.f), fmaxf(c.w - nby[it], 0.f));
          }
        }
      }
      __syncthreads();
    }
  }

  // ---- outputs ----
#pragma unroll
  for (int s = 0; s < SPB; ++s)
#pragma unroll
    for (int it = 0; it < 4; ++it) {
      unsigned long long m = __ballot((ab >> (s * 4 + it)) & 1u);
      if (ln64 == 0)
        *(unsigned long long*)&allocW[(bs0 + s) * 32 + it * 8 + wv * 2] = m;
    }
  if (tid < SPB)
    *(float4*)(capF + (bs0 + tid) * 4) = capS4[tid];
  if (g == 0) {
    float a = logpv[0] + logpv[1] + logpv[2] + logpv[3];
    for (int o = 32; o; o >>= 1) a += __shfl_xor(a, o);
    if (ln64 == 0) wredL[wv] = a;
    __syncthreads();
    if (tid == 0) out[b] = wredL[0] + wredL[1] + wredL[2] + wredL[3];
  }
}

// ---------- expand bitmask + cap to output layout ----------
__global__ __launch_bounds__(256) void k_store(const uint32_t* __restrict__ allocW,
                                               const float* __restrict__ capF,
                                               float* __restrict__ out) {
  int blk = blockIdx.x;
  if (blk < 1024) {
    int i4 = (blk * 256 + threadIdx.x) * 4;
    int b = i4 >> 18;
    int u = (i4 >> 8) & 1023;
    int s = i4 & 255;
    int base = (b * NS + s) * 32 + (u >> 5);
    uint32_t bitm = 1u << (u & 31);
    float4 o;
    o.x = (allocW[base] & bitm) ? 1.f : 0.f;
    o.y = (allocW[base + 32] & bitm) ? 1.f : 0.f;
    o.z = (allocW[base + 64] & bitm) ? 1.f : 0.f;
    o.w = (allocW[base + 96] & bitm) ? 1.f : 0.f;
    *(float4*)(out + 4 + i4) = o;
  } else {
    int b = blk - 1024;
    int s = threadIdx.x;
    float4 c = *(const float4*)(capF + (b * NS + s) * 4);
    *(float4*)(out + 4 + NB * NU * NS + (b * NS + s) * 4) = c;
  }
}

extern "C" void kernel_launch(void* const* d_in, const int* in_sizes, int n_in,
                              void* d_out, int out_size, void* d_ws, size_t ws_size,
                              hipStream_t stream) {
  const float* user_enc = (const float*)d_in[0];
  const float* server_enc = (const float*)d_in[1];
  const float* users = (const float*)d_in[2];
  const float* servers = (const float*)d_in[3];
  const uint8_t* connect = (const uint8_t*)d_in[4];
  const float* fd_onehot = (const float*)d_in[5];
  const float* W_state = (const float*)d_in[6];
  const float* b_state = (const float*)d_in[7];
  const float* W_q = (const float*)d_in[8];
  const float* W_k = (const float*)d_in[9];
  const float* W_us = (const float*)d_in[10];
  const float* fd_alpha = (const float*)d_in[11];
  const float* fd_beta = (const float*)d_in[12];
  const float* score_bias = (const float*)d_in[13];

  char* ws = (char*)d_ws;
  size_t off = 0;
  auto take = [&](size_t bytes) -> void* {
    size_t cur = off;
    off = (off + bytes + 255) & ~(size_t)255;
    return (void*)(ws + cur);
  };
  unsigned* ctrl = (unsigned*)take(4096);
  unsigned* det = ctrl + 256;
  unsigned long long* propA = (unsigned long long*)take((size_t)2 * NB * NS * 8);
  unsigned long long* propB = (unsigned long long*)take((size_t)2 * NB * NS * 8);
  float* q = (float*)take((size_t)NB * NU * ND * 4);
  float* kb = (float*)take((size_t)NB * NS * ND * 4);
  float* L0T = (float*)take((size_t)NB * NS * NU * 4);
  float* qc = (float*)take((size_t)NB * NU * 4 * 4);
  float* WS_K = (float*)take((size_t)ND * 4 * 4);
  uint32_t* connT = (uint32_t*)take((size_t)NB * NS * 32 * 4);
  uint32_t* allocW = (uint32_t*)take((size_t)NB * NS * 32 * 4);
  float* capF = (float*)take((size_t)NB * NS * 4 * 4);
  float* outp = (float*)d_out;

  // zero ctrl + both proposal buffers (epoch 0 never matches) — one contiguous range
  hipMemsetAsync(ctrl, 0, 4096 + 2 * (size_t)2 * NB * NS * 8 + 512, stream);
  k_detect<<<64, 256, 0, stream>>>(connect, det);
  k_transpose<<<128, 256, 0, stream>>>(connect, det, connT);
  k_weights<<<1, 256, 0, stream>>>(W_state, W_k, WS_K);
  // q = user_enc @ W_q^T : M=4096 N=256 K=256
  k_gemm128<<<dim3(ND / 64, (NB * NU) / 128, 1), 256, 0, stream>>>(
      user_enc, W_q, q, ND, ND, ND, ND, 0, 0, 0, nullptr, 1.f);
  // kb = (server_enc + b_state) @ W_k^T : M=1024
  k_gemm128<<<dim3(ND / 64, (NB * NS) / 128, 1), 256, 0, stream>>>(
      server_enc, W_k, kb, ND, ND, ND, ND, 0, 0, 0, b_state, 1.f);
  k_qc<<<NB * NU / 4, 256, 0, stream>>>(q, WS_K, qc);
  // L0T[b] = inv_sqrt_d * kb[b] (SxD) @ q[b]^T (DxU)
  k_gemm128<<<dim3(NU / 64, NS / 128, NB), 256, 0, stream>>>(
      kb, q, L0T, ND, ND, ND, NU,
      (long)NS * ND, (long)NU * ND, (long)NS * NU, nullptr, 0.0625f);

  // 256 blocks <= 256 CUs: co-residency guaranteed unconditionally
  k_steps4<<<dim3(NB * NGRP), dim3(256), 0, stream>>>(
      L0T, qc, users, servers, connT, fd_onehot, W_us, fd_alpha, fd_beta, score_bias,
      propA, propB, allocW, capF, outp);

  k_store<<<1028, 256, 0, stream>>>(allocW, capF, (float*)d_out);
}

// Round 11
// 232.100 us; speedup vs baseline: 1.3648x; 1.3648x over previous
//
#include <hip/hip_runtime.h>
#include <stdint.h>
#include <math.h>

#define NB 4
#define NU 1024
#define NS 256
#define NF 16
#define ND 256
#define NEGV -1000000000.0f
#define VBIT (1u << 14)
#define AGENT __HIP_MEMORY_SCOPE_AGENT
#define SPINCAP (1 << 20)
#define NGRP 64            // blocks per batch
#define SPB 4              // servers per block

// propA[par+bs]: bits0-9 argu | 10-13 fid | 14 valid | 15-20 epoch ; maxv bits << 32
// propB[par+bs]: low32 = -log(sum) bits ; high32 = epoch

// ---- shared 128x64 f32 GEMM body (double-buffered LDS; accumulation order fixed,
//      bit-identical to prior rounds' k_gemm128) ----
__device__ __forceinline__ void gemm128_body(
    const float* __restrict__ A, const float* __restrict__ Bm, float* __restrict__ C,
    int K, int lda, int ldb, int ldc, const float* __restrict__ biasA, float alpha,
    int m0, int n0, int t,
    float (&As)[2][16][132], float (&Bs)[2][16][68]) {
  int tx = t & 15, ty = t >> 4;
  float acc[8][4];
#pragma unroll
  for (int i = 0; i < 8; i++)
#pragma unroll
    for (int j = 0; j < 4; j++) acc[i][j] = 0.f;
  int ar = t >> 1;
  int akq = (t & 1) * 8;
  int br = t >> 2;
  int bkq = (t & 3) * 4;
  {
    float4 a0 = *(const float4*)(A + (size_t)(m0 + ar) * lda + akq);
    float4 a1 = *(const float4*)(A + (size_t)(m0 + ar) * lda + akq + 4);
    if (biasA) {
      const float* bp = biasA + akq;
      a0.x += bp[0]; a0.y += bp[1]; a0.z += bp[2]; a0.w += bp[3];
      a1.x += bp[4]; a1.y += bp[5]; a1.z += bp[6]; a1.w += bp[7];
    }
    As[0][akq + 0][ar] = a0.x; As[0][akq + 1][ar] = a0.y;
    As[0][akq + 2][ar] = a0.z; As[0][akq + 3][ar] = a0.w;
    As[0][akq + 4][ar] = a1.x; As[0][akq + 5][ar] = a1.y;
    As[0][akq + 6][ar] = a1.z; As[0][akq + 7][ar] = a1.w;
    float4 bv = *(const float4*)(Bm + (size_t)(n0 + br) * ldb + bkq);
    Bs[0][bkq + 0][br] = bv.x; Bs[0][bkq + 1][br] = bv.y;
    Bs[0][bkq + 2][br] = bv.z; Bs[0][bkq + 3][br] = bv.w;
  }
  __syncthreads();
  int nt = K >> 4;
  for (int ti = 0; ti < nt; ++ti) {
    int buf = ti & 1;
    float4 a0n, a1n, bvn;
    bool more = (ti + 1 < nt);
    if (more) {
      int k0 = (ti + 1) << 4;
      a0n = *(const float4*)(A + (size_t)(m0 + ar) * lda + k0 + akq);
      a1n = *(const float4*)(A + (size_t)(m0 + ar) * lda + k0 + akq + 4);
      if (biasA) {
        const float* bp = biasA + k0 + akq;
        a0n.x += bp[0]; a0n.y += bp[1]; a0n.z += bp[2]; a0n.w += bp[3];
        a1n.x += bp[4]; a1n.y += bp[5]; a1n.z += bp[6]; a1n.w += bp[7];
      }
      bvn = *(const float4*)(Bm + (size_t)(n0 + br) * ldb + k0 + bkq);
    }
#pragma unroll
    for (int k = 0; k < 16; ++k) {
      float4 aA = *(const float4*)&As[buf][k][ty * 8];
      float4 aB = *(const float4*)&As[buf][k][ty * 8 + 4];
      float4 bb = *(const float4*)&Bs[buf][k][tx * 4];
      float am[8] = {aA.x, aA.y, aA.z, aA.w, aB.x, aB.y, aB.z, aB.w};
      float bn[4] = {bb.x, bb.y, bb.z, bb.w};
#pragma unroll
      for (int i = 0; i < 8; ++i)
#pragma unroll
        for (int j = 0; j < 4; ++j) acc[i][j] += am[i] * bn[j];
    }
    if (more) {
      __syncthreads();
      int nb = buf ^ 1;
      As[nb][akq + 0][ar] = a0n.x; As[nb][akq + 1][ar] = a0n.y;
      As[nb][akq + 2][ar] = a0n.z; As[nb][akq + 3][ar] = a0n.w;
      As[nb][akq + 4][ar] = a1n.x; As[nb][akq + 5][ar] = a1n.y;
      As[nb][akq + 6][ar] = a1n.z; As[nb][akq + 7][ar] = a1n.w;
      Bs[nb][bkq + 0][br] = bvn.x; Bs[nb][bkq + 1][br] = bvn.y;
      Bs[nb][bkq + 2][br] = bvn.z; Bs[nb][bkq + 3][br] = bvn.w;
      __syncthreads();
    }
  }
#pragma unroll
  for (int i = 0; i < 8; ++i) {
    float4 o = make_float4(acc[i][0] * alpha, acc[i][1] * alpha,
                           acc[i][2] * alpha, acc[i][3] * alpha);
    *(float4*)(C + (size_t)(m0 + ty * 8 + i) * ldc + n0 + tx * 4) = o;
  }
}

// ---- pre1: transpose(+local dtype detect) | weights | q-gemm | kb-gemm | prop-zero ----
__global__ __launch_bounds__(256) void k_pre1(
    const uint8_t* __restrict__ conn, const float* __restrict__ W_state,
    const float* __restrict__ W_k, const float* __restrict__ user_enc,
    const float* __restrict__ server_enc, const float* __restrict__ b_state,
    const float* __restrict__ W_q,
    uint32_t* __restrict__ connT, float* __restrict__ WS_K,
    float* __restrict__ q, float* __restrict__ kb, float4* __restrict__ propZ) {
  __shared__ float As[2][16][132];
  __shared__ float Bs[2][16][68];
  int blk = blockIdx.x;
  int t = threadIdx.x;
  if (blk < 128) {
    // local dtype detect on first 16KB of conn (global property; redundant per block)
    __shared__ unsigned dd[2];
    unsigned c0 = 0, c123 = 0;
    for (int i = t; i < 4096; i += 256) {
      uchar4 v = ((const uchar4*)conn)[i];
      c0 |= v.x; c123 |= (unsigned)(v.y | v.z | v.w);
    }
    if (t == 0) { dd[0] = 0; dd[1] = 0; }
    __syncthreads();
    unsigned long long m0 = __ballot(c0 != 0), m1 = __ballot(c123 != 0);
    if ((t & 63) == 0) {
      if (m0) atomicOr(&dd[0], 1u);
      if (m1) atomicOr(&dd[1], 1u);
    }
    __syncthreads();
    int f = (dd[1] == 0) ? 0 : ((dd[0] == 0) ? 1 : 2);
    int b = blk >> 5, ug = blk & 31;
    int u0 = ug * 32;
    uint8_t* sm = (uint8_t*)&As[0][0][0];   // 8320B < 16896B
#pragma unroll 4
    for (int r = 0; r < 32; ++r) {
      int e = (b * NU + u0 + r) * NS + t;
      bool nz;
      if (f == 0)      nz = ((const int*)conn)[e] != 0;
      else if (f == 1) nz = ((const float*)conn)[e] != 0.0f;
      else             nz = conn[e] != 0;
      sm[r * 260 + t] = nz ? 1 : 0;
    }
    __syncthreads();
    uint32_t word = 0;
#pragma unroll
    for (int j = 0; j < 32; ++j) word |= (uint32_t)sm[j * 260 + t] << j;
    connT[(b * NS + t) * 32 + ug] = word;
  } else if (blk == 128) {
    int d = t;
    const float4* wk4 = (const float4*)(W_k + d * ND);
    const float4* ws4 = (const float4*)W_state;
    float a0 = 0, a1 = 0, a2 = 0, a3 = 0;
    for (int e4 = 0; e4 < ND / 4; ++e4) {
      float4 k4 = wk4[e4];
      float4 w0 = ws4[e4 * 4 + 0];
      a0 += k4.x * w0.x; a1 += k4.x * w0.y; a2 += k4.x * w0.z; a3 += k4.x * w0.w;
      float4 w1 = ws4[e4 * 4 + 1];
      a0 += k4.y * w1.x; a1 += k4.y * w1.y; a2 += k4.y * w1.z; a3 += k4.y * w1.w;
      float4 w2 = ws4[e4 * 4 + 2];
      a0 += k4.z * w2.x; a1 += k4.z * w2.y; a2 += k4.z * w2.z; a3 += k4.z * w2.w;
      float4 w3 = ws4[e4 * 4 + 3];
      a0 += k4.w * w3.x; a1 += k4.w * w3.y; a2 += k4.w * w3.z; a3 += k4.w * w3.w;
    }
    ((float4*)WS_K)[d] = make_float4(a0, a1, a2, a3);
  } else if (blk < 257) {
    int idx = blk - 129;           // q-gemm: M=4096, N=256
    gemm128_body(user_enc, W_q, q, ND, ND, ND, ND, nullptr, 1.f,
                 (idx >> 2) * 128, (idx & 3) * 64, t, As, Bs);
  } else if (blk < 289) {
    int idx = blk - 257;           // kb-gemm: M=1024, N=256
    gemm128_body(server_enc, W_k, kb, ND, ND, ND, ND, b_state, 1.f,
                 (idx >> 2) * 128, (idx & 3) * 64, t, As, Bs);
  } else {
    float4 z = make_float4(0.f, 0.f, 0.f, 0.f);
    for (int i = t; i < 2048; i += 256) propZ[i] = z;   // propA+propB 32KB contiguous
  }
}

// ---- pre2: qc | L0T-gemm ----
__global__ __launch_bounds__(256) void k_pre2(const float* __restrict__ q,
                                              const float* __restrict__ WS_K,
                                              float* __restrict__ qc,
                                              const float* __restrict__ kb,
                                              float* __restrict__ L0T) {
  __shared__ float As[2][16][132];
  __shared__ float Bs[2][16][68];
  int blk = blockIdx.x;
  int t = threadIdx.x;
  if (blk < 1024) {
    int row = blk * 4 + (t >> 6);
    int ln = t & 63;
    const float* qr = q + (size_t)row * ND;
    float a0 = 0, a1 = 0, a2 = 0, a3 = 0;
    for (int d = ln; d < ND; d += 64) {
      float qv = qr[d];
      float4 w = ((const float4*)WS_K)[d];
      a0 += qv * w.x; a1 += qv * w.y; a2 += qv * w.z; a3 += qv * w.w;
    }
    for (int o = 32; o; o >>= 1) {
      a0 += __shfl_xor(a0, o); a1 += __shfl_xor(a1, o);
      a2 += __shfl_xor(a2, o); a3 += __shfl_xor(a3, o);
    }
    if (ln == 0)
      ((float4*)qc)[row] = make_float4(a0 * 0.0625f, a1 * 0.0625f, a2 * 0.0625f, a3 * 0.0625f);
  } else {
    int idx = blk - 1024;          // L0T: per batch z, M=NS, N=NU
    int n0 = (idx & 15) * 64;
    int m0 = ((idx >> 4) & 1) * 128;
    int z = idx >> 5;
    gemm128_body(kb + (size_t)z * NS * ND, q + (size_t)z * NU * ND,
                 L0T + (size_t)z * NS * NU, ND, ND, ND, NU, nullptr, 0.0625f,
                 m0, n0, t, As, Bs);
  }
}

// ---- the 32-step allocator: 4 servers/block, 64 blocks/batch, epoch-tagged
//      proposals, 4-way banked LDS atomics, fused output epilogue ----
__global__ __launch_bounds__(256) void k_steps4(
    const float* __restrict__ L0T, const float* __restrict__ qc,
    const float* __restrict__ users, const float* __restrict__ servers,
    const uint32_t* __restrict__ connT, const float* __restrict__ fd_onehot,
    const float* __restrict__ W_us, const float* __restrict__ fd_alpha,
    const float* __restrict__ fd_beta, const float* __restrict__ score_bias,
    unsigned long long* __restrict__ propA, unsigned long long* __restrict__ propB,
    float* __restrict__ out) {
  __shared__ float redM[SPB][256];
  __shared__ int redA[SPB][256];
  __shared__ unsigned keyEnc4[4][NU];
  __shared__ unsigned srvMin4[4][NU];
  __shared__ float lsum4[4][NU];
  __shared__ unsigned fdSh4[4][NU];
  __shared__ float4 capS4[SPB];
  __shared__ float4 crS4[SPB];
  __shared__ float4 minv4[SPB];
  __shared__ int fidS[SPB];
  __shared__ float bM[SPB];
  __shared__ int bA[SPB];
  __shared__ float wredL[4];
  __shared__ int anyL[4];

  const int blk = blockIdx.x;
  const int b = blk >> 6;
  const int g = blk & 63;
  const int tid = threadIdx.x;
  const int wv = tid >> 6, ln64 = tid & 63;
  const int sg = tid >> 6;
  const int bs0 = b * NS + g * SPB;
  const int bank = tid & 3;

  const float a_ = fd_alpha[0], be_ = fd_beta[0];
  const float t0 = tanhf(be_), t1 = tanhf(a_ + be_);
  const float sb = score_bias[0];
  const float w0 = W_us[0], w1 = W_us[1], w2 = W_us[2];

  if (tid < SPB) {
    int srow = bs0 + tid;
    int f = 0;
    for (int ff = 0; ff < NF; ++ff)
      if (fd_onehot[srow * NF + ff] > 0.5f) { f = ff; break; }
    fidS[tid] = f;
    float4 ic = make_float4(servers[srow * 8 + 3], servers[srow * 8 + 4],
                            servers[srow * 8 + 5], servers[srow * 8 + 6]);
    capS4[tid] = ic;
    float4 mv = make_float4(fmaxf(ic.x, 1e-6f), fmaxf(ic.y, 1e-6f),
                            fmaxf(ic.z, 1e-6f), fmaxf(ic.w, 1e-6f));
    minv4[tid] = mv;
    crS4[tid] = make_float4(ic.x / mv.x, ic.y / mv.y, ic.z / mv.z, ic.w / mv.w);
  }

  float qc0[4], qc1[4], qc2[4], qc3[4], nax[4], nay[4], nbx[4], nby[4];
  float L0r[SPB][4];
  uint32_t upk[4] = {0, 0, 0, 0};   // bits 0-15 fdmask, bits 16-17 rc
  float usv[4];
  float logpv[4] = {0, 0, 0, 0};
  uint32_t cb = 0, ab = 0;
#pragma unroll
  for (int it = 0; it < 4; ++it) {
    int u = it * 256 + tid, gu = b * NU + u;
    float4 q4 = *(const float4*)(qc + gu * 4);
    qc0[it] = q4.x; qc1[it] = q4.y; qc2[it] = q4.z; qc3[it] = q4.w;
    float2 nA = *(const float2*)(users + gu * 8 + 2);
    float2 nB2 = *(const float2*)(users + gu * 8 + 4);
    nax[it] = nA.x; nay[it] = nA.y; nbx[it] = nB2.x; nby[it] = nB2.y;
    usv[it] = w1;
  }
#pragma unroll
  for (int s = 0; s < SPB; ++s)
#pragma unroll
    for (int it = 0; it < 4; ++it) {
      L0r[s][it] = L0T[(size_t)(bs0 + s) * NU + it * 256 + tid];
      uint32_t word = connT[(bs0 + s) * 32 + it * 8 + (tid >> 5)];
      cb |= ((word >> (tid & 31)) & 1u) << (s * 4 + it);
    }
  for (int i = tid; i < 4 * NU; i += 256) {
    (&keyEnc4[0][0])[i] = 0u;
    (&srvMin4[0][0])[i] = 0xFFFFFFFFu;
    (&lsum4[0][0])[i] = 0.f;
    (&fdSh4[0][0])[i] = 0u;
  }
  __syncthreads();

  for (int step = 0; step < 32; ++step) {
    unsigned e = (unsigned)(step + 1);
    // ---- phase A: masked argmax (propA stored early; lse deferred) ----
    float cand[SPB][4];
#pragma unroll
    for (int s = 0; s < SPB; ++s) {
      float4 c = capS4[s];
      float4 cr = crS4[s];
      int fid = fidS[s];
      float m = NEGV; int a = 0x7fffffff;
#pragma unroll
      for (int it = 0; it < 4; ++it) {
        int u = it * 256 + tid;
        bool el = ((cb >> (s * 4 + it)) & 1u) && !((ab >> (s * 4 + it)) & 1u) &&
                  ((upk[it] & 0x30000u) != 0x30000u) &&
                  c.x >= nax[it] && c.y >= nay[it] && c.z >= nbx[it] && c.w >= nby[it];
        float tt = ((upk[it] >> fid) & 1u) ? t0 : t1;
        float lg = L0r[s][it] + qc0[it] * cr.x + qc1[it] * cr.y + qc2[it] * cr.z +
                   qc3[it] * cr.w + sb + tt + usv[it];
        float cv = el ? lg : NEGV;
        cand[s][it] = cv;
        if (cv > m || (cv == m && u < a)) { m = cv; a = u; }
      }
      redM[s][tid] = m; redA[s][tid] = a;
    }
    __syncthreads();
    {
      float m = redM[sg][ln64 * 4]; int a = redA[sg][ln64 * 4];
#pragma unroll
      for (int j = 1; j < 4; ++j) {
        float v = redM[sg][ln64 * 4 + j]; int aa = redA[sg][ln64 * 4 + j];
        if (v > m || (v == m && aa < a)) { m = v; a = aa; }
      }
      for (int o = 32; o; o >>= 1) {
        float ov = __shfl_xor(m, o); int oa = __shfl_xor(a, o);
        if (ov > m || (ov == m && oa < a)) { m = ov; a = oa; }
      }
      if (ln64 == 0) {
        bM[sg] = m; bA[sg] = a;
        unsigned validb = (m > -1e8f) ? VBIT : 0u;
        unsigned pinfo = (unsigned)a | ((unsigned)fidS[sg] << 10) | validb | (e << 15);
        unsigned long long Aw = (unsigned long long)pinfo |
                                ((unsigned long long)__float_as_uint(m) << 32);
        __hip_atomic_store(&propA[(step & 1) * (NB * NS) + bs0 + sg], Aw,
                           __ATOMIC_RELAXED, AGENT);
      }
    }
    __syncthreads();
    // deferred lse -> propB
#pragma unroll
    for (int s = 0; s < SPB; ++s) {
      float mv = bM[s];
      redM[s][tid] = expf(cand[s][0] - mv) + expf(cand[s][1] - mv) +
                     expf(cand[s][2] - mv) + expf(cand[s][3] - mv);
    }
    __syncthreads();
    {
      float ps = redM[sg][ln64 * 4];
#pragma unroll
      for (int j = 1; j < 4; ++j) ps += redM[sg][ln64 * 4 + j];
      for (int o = 32; o; o >>= 1) ps += __shfl_xor(ps, o);
      if (ln64 == 0) {
        unsigned long long Bw = (unsigned long long)__float_as_uint(-logf(ps)) |
                                ((unsigned long long)e << 32);
        __hip_atomic_store(&propB[(step & 1) * (NB * NS) + bs0 + sg], Bw,
                           __ATOMIC_RELAXED, AGENT);
      }
    }

    // ---- phase B: poll own slot, banked winner resolution ----
    {
      int par = (step & 1) * (NB * NS) + b * NS;
      unsigned long long Aw;
      {
        int iters = 0;
        for (;;) {
          Aw = __hip_atomic_load(&propA[par + tid], __ATOMIC_RELAXED, AGENT);
          if ((((unsigned)Aw >> 15) & 63u) == e) break;
          __builtin_amdgcn_s_sleep(1);
          if (++iters > SPINCAP) break;
        }
      }
      unsigned pi = (unsigned)Aw;
      int pu = pi & 1023;
      unsigned encv = 0;
      if (pi & VBIT) {
        unsigned vb = (unsigned)(Aw >> 32);
        encv = (vb & 0x80000000u) ? ~vb : (vb | 0x80000000u);
        atomicMax(&keyEnc4[bank][pu], encv);
      }
      unsigned long long mm = __ballot((pi & VBIT) != 0);
      if (ln64 == 0) anyL[wv] = (mm != 0ull) ? 1 : 0;
      __syncthreads();
      if (!(anyL[0] | anyL[1] | anyL[2] | anyL[3])) break;  // batch frozen forever
      if (pi & VBIT) {
        if (keyEnc4[bank][pu] == encv) atomicMin(&srvMin4[bank][pu], (unsigned)tid);
        unsigned long long Bw;
        int iters = 0;
        for (;;) {
          Bw = __hip_atomic_load(&propB[par + tid], __ATOMIC_RELAXED, AGENT);
          if ((unsigned)(Bw >> 32) == e) break;
          __builtin_amdgcn_s_sleep(1);
          if (++iters > SPINCAP) break;
        }
        atomicAdd(&lsum4[bank][pu], __uint_as_float((unsigned)Bw));
        atomicOr(&fdSh4[bank][pu], 1u << ((pi >> 10) & 15));
      }
      __syncthreads();
#pragma unroll
      for (int it = 0; it < 4; ++it) {
        int u = it * 256 + tid;
        unsigned k0 = keyEnc4[0][u], k1 = keyEnc4[1][u];
        unsigned k2 = keyEnc4[2][u], k3 = keyEnc4[3][u];
        unsigned gmax = max(max(k0, k1), max(k2, k3));
        if (gmax) {
          unsigned win = 0xFFFFFFFFu;
          if (k0 == gmax) win = min(win, srvMin4[0][u]);
          if (k1 == gmax) win = min(win, srvMin4[1][u]);
          if (k2 == gmax) win = min(win, srvMin4[2][u]);
          if (k3 == gmax) win = min(win, srvMin4[3][u]);
          float ls = lsum4[0][u] + lsum4[1][u] + lsum4[2][u] + lsum4[3][u];
          unsigned fda = fdSh4[0][u] | fdSh4[1][u] | fdSh4[2][u] | fdSh4[3][u];
          keyEnc4[0][u] = 0u; keyEnc4[1][u] = 0u; keyEnc4[2][u] = 0u; keyEnc4[3][u] = 0u;
          srvMin4[0][u] = 0xFFFFFFFFu; srvMin4[1][u] = 0xFFFFFFFFu;
          srvMin4[2][u] = 0xFFFFFFFFu; srvMin4[3][u] = 0xFFFFFFFFu;
          lsum4[0][u] = 0.f; lsum4[1][u] = 0.f; lsum4[2][u] = 0.f; lsum4[3][u] = 0.f;
          fdSh4[0][u] = 0u; fdSh4[1][u] = 0u; fdSh4[2][u] = 0u; fdSh4[3][u] = 0u;
          logpv[it] += ls;
          uint32_t pk = upk[it];
          int r = (int)((pk >> 16) & 3) + 1;
          upk[it] = ((pk | fda) & 0xFFFFu) | ((uint32_t)r << 16);
          float rf = (float)r;
          usv[it] = w0 * (rf / 3.0f) + w1 * (fmaxf(3.0f - rf, 0.f) / 3.0f) +
                    ((r == 2) ? w2 : 0.f);
          if ((int)(win >> 2) == g) {
            int sl = win & 3;
            ab |= 1u << (sl * 4 + it);
            float4 c = capS4[sl];        // unique (server,step) winner -> no race
            float4 nc = make_float4(fmaxf(c.x - nax[it], 0.f), fmaxf(c.y - nay[it], 0.f),
                                    fmaxf(c.z - nbx[it], 0.f), fmaxf(c.w - nby[it], 0.f));
            capS4[sl] = nc;
            float4 mv = minv4[sl];
            crS4[sl] = make_float4(nc.x / mv.x, nc.y / mv.y, nc.z / mv.z, nc.w / mv.w);
          }
        }
      }
      __syncthreads();
    }
  }

  // ---- fused outputs: alloc expansion + cap + logp ----
#pragma unroll
  for (int it = 0; it < 4; ++it) {
    int u = it * 256 + tid;
    float4 o;
    o.x = ((ab >> (0 * 4 + it)) & 1u) ? 1.f : 0.f;
    o.y = ((ab >> (1 * 4 + it)) & 1u) ? 1.f : 0.f;
    o.z = ((ab >> (2 * 4 + it)) & 1u) ? 1.f : 0.f;
    o.w = ((ab >> (3 * 4 + it)) & 1u) ? 1.f : 0.f;
    *(float4*)(out + 4 + (size_t)(b * NU + u) * NS + g * 4) = o;
  }
  if (tid < SPB)
    *(float4*)(out + 4 + (size_t)NB * NU * NS + (size_t)(bs0 + tid) * 4) = capS4[tid];
  if (g == 0) {
    float a2 = logpv[0] + logpv[1] + logpv[2] + logpv[3];
    for (int o = 32; o; o >>= 1) a2 += __shfl_xor(a2, o);
    if (ln64 == 0) wredL[wv] = a2;
    __syncthreads();
    if (tid == 0) out[b] = wredL[0] + wredL[1] + wredL[2] + wredL[3];
  }
}

extern "C" void kernel_launch(void* const* d_in, const int* in_sizes, int n_in,
                              void* d_out, int out_size, void* d_ws, size_t ws_size,
                              hipStream_t stream) {
  const float* user_enc = (const float*)d_in[0];
  const float* server_enc = (const float*)d_in[1];
  const float* users = (const float*)d_in[2];
  const float* servers = (const float*)d_in[3];
  const uint8_t* connect = (const uint8_t*)d_in[4];
  const float* fd_onehot = (const float*)d_in[5];
  const float* W_state = (const float*)d_in[6];
  const float* b_state = (const float*)d_in[7];
  const float* W_q = (const float*)d_in[8];
  const float* W_k = (const float*)d_in[9];
  const float* W_us = (const float*)d_in[10];
  const float* fd_alpha = (const float*)d_in[11];
  const float* fd_beta = (const float*)d_in[12];
  const float* score_bias = (const float*)d_in[13];

  char* ws = (char*)d_ws;
  size_t off = 0;
  auto take = [&](size_t bytes) -> void* {
    size_t cur = off;
    off = (off + bytes + 255) & ~(size_t)255;
    return (void*)(ws + cur);
  };
  unsigned long long* propA = (unsigned long long*)take((size_t)2 * NB * NS * 8);  // 16KB
  unsigned long long* propB = (unsigned long long*)take((size_t)2 * NB * NS * 8);  // 16KB (contiguous)
  float* q = (float*)take((size_t)NB * NU * ND * 4);
  float* kb = (float*)take((size_t)NB * NS * ND * 4);
  float* L0T = (float*)take((size_t)NB * NS * NU * 4);
  float* qc = (float*)take((size_t)NB * NU * 4 * 4);
  float* WS_K = (float*)take((size_t)ND * 4 * 4);
  uint32_t* connT = (uint32_t*)take((size_t)NB * NS * 32 * 4);
  float* outp = (float*)d_out;

  // 3 dispatches total
  k_pre1<<<290, 256, 0, stream>>>(connect, W_state, W_k, user_enc, server_enc, b_state,
                                  W_q, connT, WS_K, q, kb, (float4*)propA);
  k_pre2<<<1152, 256, 0, stream>>>(q, WS_K, qc, kb, L0T);
  k_steps4<<<NB * NGRP, 256, 0, stream>>>(
      L0T, qc, users, servers, connT, fd_onehot, W_us, fd_alpha, fd_beta, score_bias,
      propA, propB, outp);
}

// Round 12
// 226.313 us; speedup vs baseline: 1.3997x; 1.0256x over previous
//
#include <hip/hip_runtime.h>
#include <stdint.h>
#include <math.h>

#define NB 4
#define NU 1024
#define NS 256
#define NF 16
#define ND 256
#define NEGV -1000000000.0f
#define VBIT (1u << 14)
#define AGENT __HIP_MEMORY_SCOPE_AGENT
#define SPINCAP (1 << 20)
#define NGRP 64            // blocks per batch
#define SPB 4              // servers per block

// propA[par+bs]: bits0-9 argu | 10-13 fid | 14 valid | 15-20 epoch ; maxv bits << 32
// propB[par+bs]: low32 = -log(sum) bits ; high32 = epoch

// ---- shared 64x64 f32 GEMM body (double-buffered LDS; proven bit-identical,
//      rounds 5-8) ----
__device__ __forceinline__ void gemm64_body(
    const float* __restrict__ A, const float* __restrict__ Bm, float* __restrict__ C,
    int K, int lda, int ldb, int ldc, const float* __restrict__ biasA, float alpha,
    int m0, int n0, int t,
    float (&As)[2][16][68], float (&Bs)[2][16][68]) {
  int tx = t & 15, ty = t >> 4;
  float acc[4][4];
#pragma unroll
  for (int i = 0; i < 4; i++)
#pragma unroll
    for (int j = 0; j < 4; j++) acc[i][j] = 0.f;
  int lr = t >> 2;
  int kq = (t & 3) * 4;
  {
    float4 av = *(const float4*)(A + (size_t)(m0 + lr) * lda + kq);
    if (biasA) {
      const float* bp = biasA + kq;
      av.x += bp[0]; av.y += bp[1]; av.z += bp[2]; av.w += bp[3];
    }
    As[0][kq + 0][lr] = av.x; As[0][kq + 1][lr] = av.y;
    As[0][kq + 2][lr] = av.z; As[0][kq + 3][lr] = av.w;
    float4 bv = *(const float4*)(Bm + (size_t)(n0 + lr) * ldb + kq);
    Bs[0][kq + 0][lr] = bv.x; Bs[0][kq + 1][lr] = bv.y;
    Bs[0][kq + 2][lr] = bv.z; Bs[0][kq + 3][lr] = bv.w;
  }
  __syncthreads();
  int nt = K >> 4;
  for (int ti = 0; ti < nt; ++ti) {
    int buf = ti & 1;
    float4 av2, bv2;
    bool more = (ti + 1 < nt);
    if (more) {
      int k0 = (ti + 1) << 4;
      av2 = *(const float4*)(A + (size_t)(m0 + lr) * lda + k0 + kq);
      if (biasA) {
        const float* bp = biasA + k0 + kq;
        av2.x += bp[0]; av2.y += bp[1]; av2.z += bp[2]; av2.w += bp[3];
      }
      bv2 = *(const float4*)(Bm + (size_t)(n0 + lr) * ldb + k0 + kq);
    }
#pragma unroll
    for (int k = 0; k < 16; ++k) {
      float4 a = *(const float4*)&As[buf][k][ty * 4];
      float4 bb = *(const float4*)&Bs[buf][k][tx * 4];
      float am[4] = {a.x, a.y, a.z, a.w};
      float bn[4] = {bb.x, bb.y, bb.z, bb.w};
#pragma unroll
      for (int i = 0; i < 4; ++i)
#pragma unroll
        for (int j = 0; j < 4; ++j) acc[i][j] += am[i] * bn[j];
    }
    if (more) {
      __syncthreads();
      int nb = buf ^ 1;
      As[nb][kq + 0][lr] = av2.x; As[nb][kq + 1][lr] = av2.y;
      As[nb][kq + 2][lr] = av2.z; As[nb][kq + 3][lr] = av2.w;
      Bs[nb][kq + 0][lr] = bv2.x; Bs[nb][kq + 1][lr] = bv2.y;
      Bs[nb][kq + 2][lr] = bv2.z; Bs[nb][kq + 3][lr] = bv2.w;
      __syncthreads();
    }
  }
#pragma unroll
  for (int i = 0; i < 4; ++i) {
    float4 o = make_float4(acc[i][0] * alpha, acc[i][1] * alpha,
                           acc[i][2] * alpha, acc[i][3] * alpha);
    *(float4*)(C + (size_t)(m0 + ty * 4 + i) * ldc + n0 + tx * 4) = o;
  }
}

// ---- pre1: transpose(+local dtype detect) | weights | q-gemm | kb-gemm | prop-zero ----
__global__ __launch_bounds__(256) void k_pre1(
    const uint8_t* __restrict__ conn, const float* __restrict__ W_state,
    const float* __restrict__ W_k, const float* __restrict__ user_enc,
    const float* __restrict__ server_enc, const float* __restrict__ b_state,
    const float* __restrict__ W_q,
    uint32_t* __restrict__ connT, float* __restrict__ WS_K,
    float* __restrict__ q, float* __restrict__ kb, float4* __restrict__ propZ) {
  __shared__ float As[2][16][68];
  __shared__ float Bs[2][16][68];
  int blk = blockIdx.x;
  int t = threadIdx.x;
  if (blk < 128) {
    __shared__ unsigned dd[2];
    unsigned c0 = 0, c123 = 0;
    for (int i = t; i < 4096; i += 256) {
      uchar4 v = ((const uchar4*)conn)[i];
      c0 |= v.x; c123 |= (unsigned)(v.y | v.z | v.w);
    }
    if (t == 0) { dd[0] = 0; dd[1] = 0; }
    __syncthreads();
    unsigned long long m0 = __ballot(c0 != 0), m1 = __ballot(c123 != 0);
    if ((t & 63) == 0) {
      if (m0) atomicOr(&dd[0], 1u);
      if (m1) atomicOr(&dd[1], 1u);
    }
    __syncthreads();
    int f = (dd[1] == 0) ? 0 : ((dd[0] == 0) ? 1 : 2);
    int b = blk >> 5, ug = blk & 31;
    int u0 = ug * 32;
    uint8_t* sm = (uint8_t*)&As[0][0][0];   // 8320B < 8704B
#pragma unroll 4
    for (int r = 0; r < 32; ++r) {
      int e = (b * NU + u0 + r) * NS + t;
      bool nz;
      if (f == 0)      nz = ((const int*)conn)[e] != 0;
      else if (f == 1) nz = ((const float*)conn)[e] != 0.0f;
      else             nz = conn[e] != 0;
      sm[r * 260 + t] = nz ? 1 : 0;
    }
    __syncthreads();
    uint32_t word = 0;
#pragma unroll
    for (int j = 0; j < 32; ++j) word |= (uint32_t)sm[j * 260 + t] << j;
    connT[(b * NS + t) * 32 + ug] = word;
  } else if (blk == 128) {
    int d = t;
    const float4* wk4 = (const float4*)(W_k + d * ND);
    const float4* ws4 = (const float4*)W_state;
    float a0 = 0, a1 = 0, a2 = 0, a3 = 0;
    for (int e4 = 0; e4 < ND / 4; ++e4) {
      float4 k4 = wk4[e4];
      float4 w0 = ws4[e4 * 4 + 0];
      a0 += k4.x * w0.x; a1 += k4.x * w0.y; a2 += k4.x * w0.z; a3 += k4.x * w0.w;
      float4 w1 = ws4[e4 * 4 + 1];
      a0 += k4.y * w1.x; a1 += k4.y * w1.y; a2 += k4.y * w1.z; a3 += k4.y * w1.w;
      float4 w2 = ws4[e4 * 4 + 2];
      a0 += k4.z * w2.x; a1 += k4.z * w2.y; a2 += k4.z * w2.z; a3 += k4.z * w2.w;
      float4 w3 = ws4[e4 * 4 + 3];
      a0 += k4.w * w3.x; a1 += k4.w * w3.y; a2 += k4.w * w3.z; a3 += k4.w * w3.w;
    }
    ((float4*)WS_K)[d] = make_float4(a0, a1, a2, a3);
  } else if (blk < 385) {
    int idx = blk - 129;           // q-gemm: M=4096, N=256 -> 64x4 tiles = 256 blocks
    gemm64_body(user_enc, W_q, q, ND, ND, ND, ND, nullptr, 1.f,
                (idx >> 2) * 64, (idx & 3) * 64, t, As, Bs);
  } else if (blk < 449) {
    int idx = blk - 385;           // kb-gemm: M=1024, N=256 -> 16x4 tiles = 64 blocks
    gemm64_body(server_enc, W_k, kb, ND, ND, ND, ND, b_state, 1.f,
                (idx >> 2) * 64, (idx & 3) * 64, t, As, Bs);
  } else {
    float4 z = make_float4(0.f, 0.f, 0.f, 0.f);
    for (int i = t; i < 2048; i += 256) propZ[i] = z;   // propA+propB 32KB contiguous
  }
}

// ---- pre2: qc | L0T-gemm ----
__global__ __launch_bounds__(256) void k_pre2(const float* __restrict__ q,
                                              const float* __restrict__ WS_K,
                                              float* __restrict__ qc,
                                              const float* __restrict__ kb,
                                              float* __restrict__ L0T) {
  __shared__ float As[2][16][68];
  __shared__ float Bs[2][16][68];
  int blk = blockIdx.x;
  int t = threadIdx.x;
  if (blk < 1024) {
    int row = blk * 4 + (t >> 6);
    int ln = t & 63;
    const float* qr = q + (size_t)row * ND;
    float a0 = 0, a1 = 0, a2 = 0, a3 = 0;
    for (int d = ln; d < ND; d += 64) {
      float qv = qr[d];
      float4 w = ((const float4*)WS_K)[d];
      a0 += qv * w.x; a1 += qv * w.y; a2 += qv * w.z; a3 += qv * w.w;
    }
    for (int o = 32; o; o >>= 1) {
      a0 += __shfl_xor(a0, o); a1 += __shfl_xor(a1, o);
      a2 += __shfl_xor(a2, o); a3 += __shfl_xor(a3, o);
    }
    if (ln == 0)
      ((float4*)qc)[row] = make_float4(a0 * 0.0625f, a1 * 0.0625f, a2 * 0.0625f, a3 * 0.0625f);
  } else {
    int idx = blk - 1024;          // L0T: per batch z, M=NS (4 tiles), N=NU (16 tiles)
    int z = idx >> 6;
    int rest = idx & 63;
    int m0 = (rest >> 4) * 64;
    int n0 = (rest & 15) * 64;
    gemm64_body(kb + (size_t)z * NS * ND, q + (size_t)z * NU * ND,
                L0T + (size_t)z * NS * NU, ND, ND, ND, NU, nullptr, 0.0625f,
                m0, n0, t, As, Bs);
  }
}

// ---- the 32-step allocator: 4 servers/block, 64 blocks/batch, epoch-tagged
//      proposals, banked LDS atomics, XCD-clustered mapping, fused epilogue ----
__global__ __launch_bounds__(256) void k_steps4(
    const float* __restrict__ L0T, const float* __restrict__ qc,
    const float* __restrict__ users, const float* __restrict__ servers,
    const uint32_t* __restrict__ connT, const float* __restrict__ fd_onehot,
    const float* __restrict__ W_us, const float* __restrict__ fd_alpha,
    const float* __restrict__ fd_beta, const float* __restrict__ score_bias,
    unsigned long long* __restrict__ propA, unsigned long long* __restrict__ propB,
    float* __restrict__ out) {
  __shared__ float redM[SPB][256];
  __shared__ int redA[SPB][256];
  __shared__ unsigned keyEnc4[4][NU];
  __shared__ unsigned srvMin4[4][NU];
  __shared__ float lsum4[4][NU];
  __shared__ unsigned fdSh4[4][NU];
  __shared__ float4 capS4[SPB];
  __shared__ float4 crS4[SPB];
  __shared__ float4 minv4[SPB];
  __shared__ int fidS[SPB];
  __shared__ float bM[SPB];
  __shared__ int bA[SPB];
  __shared__ float wredL[4];
  __shared__ int anyL[4];

  const int blk = blockIdx.x;
  // XCD-clustered bijection: batch b on XCD residues {2b, 2b+1}
  const int b = (blk & 7) >> 1;
  const int g = ((blk >> 3) << 1) | (blk & 1);
  const int tid = threadIdx.x;
  const int wv = tid >> 6, ln64 = tid & 63;
  const int sg = tid >> 6;
  const int bs0 = b * NS + g * SPB;
  const int bank = tid & 3;

  const float a_ = fd_alpha[0], be_ = fd_beta[0];
  const float t0 = tanhf(be_), t1 = tanhf(a_ + be_);
  const float sb = score_bias[0];
  const float w0 = W_us[0], w1 = W_us[1], w2 = W_us[2];

  if (tid < SPB) {
    int srow = bs0 + tid;
    int f = 0;
    for (int ff = 0; ff < NF; ++ff)
      if (fd_onehot[srow * NF + ff] > 0.5f) { f = ff; break; }
    fidS[tid] = f;
    float4 ic = make_float4(servers[srow * 8 + 3], servers[srow * 8 + 4],
                            servers[srow * 8 + 5], servers[srow * 8 + 6]);
    capS4[tid] = ic;
    float4 mv = make_float4(fmaxf(ic.x, 1e-6f), fmaxf(ic.y, 1e-6f),
                            fmaxf(ic.z, 1e-6f), fmaxf(ic.w, 1e-6f));
    minv4[tid] = mv;
    crS4[tid] = make_float4(ic.x / mv.x, ic.y / mv.y, ic.z / mv.z, ic.w / mv.w);
  }

  float qc0[4], qc1[4], qc2[4], qc3[4], nax[4], nay[4], nbx[4], nby[4];
  float L0r[SPB][4];
  uint32_t upk[4] = {0, 0, 0, 0};   // bits 0-15 fdmask, bits 16-17 rc
  float usv[4];
  float logpv[4] = {0, 0, 0, 0};
  uint32_t cb = 0, ab = 0;
#pragma unroll
  for (int it = 0; it < 4; ++it) {
    int u = it * 256 + tid, gu = b * NU + u;
    float4 q4 = *(const float4*)(qc + gu * 4);
    qc0[it] = q4.x; qc1[it] = q4.y; qc2[it] = q4.z; qc3[it] = q4.w;
    float2 nA = *(const float2*)(users + gu * 8 + 2);
    float2 nB2 = *(const float2*)(users + gu * 8 + 4);
    nax[it] = nA.x; nay[it] = nA.y; nbx[it] = nB2.x; nby[it] = nB2.y;
    usv[it] = w1;
  }
#pragma unroll
  for (int s = 0; s < SPB; ++s)
#pragma unroll
    for (int it = 0; it < 4; ++it) {
      L0r[s][it] = L0T[(size_t)(bs0 + s) * NU + it * 256 + tid];
      uint32_t word = connT[(bs0 + s) * 32 + it * 8 + (tid >> 5)];
      cb |= ((word >> (tid & 31)) & 1u) << (s * 4 + it);
    }
  for (int i = tid; i < 4 * NU; i += 256) {
    (&keyEnc4[0][0])[i] = 0u;
    (&srvMin4[0][0])[i] = 0xFFFFFFFFu;
    (&lsum4[0][0])[i] = 0.f;
    (&fdSh4[0][0])[i] = 0u;
  }
  __syncthreads();

  for (int step = 0; step < 32; ++step) {
    unsigned e = (unsigned)(step + 1);
    // ---- phase A: masked argmax (propA stored early; lse deferred) ----
    float cand[SPB][4];
#pragma unroll
    for (int s = 0; s < SPB; ++s) {
      float4 c = capS4[s];
      float4 cr = crS4[s];
      int fid = fidS[s];
      float m = NEGV; int a = 0x7fffffff;
#pragma unroll
      for (int it = 0; it < 4; ++it) {
        int u = it * 256 + tid;
        bool el = ((cb >> (s * 4 + it)) & 1u) && !((ab >> (s * 4 + it)) & 1u) &&
                  ((upk[it] & 0x30000u) != 0x30000u) &&
                  c.x >= nax[it] && c.y >= nay[it] && c.z >= nbx[it] && c.w >= nby[it];
        float tt = ((upk[it] >> fid) & 1u) ? t0 : t1;
        float lg = L0r[s][it] + qc0[it] * cr.x + qc1[it] * cr.y + qc2[it] * cr.z +
                   qc3[it] * cr.w + sb + tt + usv[it];
        float cv = el ? lg : NEGV;
        cand[s][it] = cv;
        if (cv > m || (cv == m && u < a)) { m = cv; a = u; }
      }
      redM[s][tid] = m; redA[s][tid] = a;
    }
    __syncthreads();
    {
      float m = redM[sg][ln64 * 4]; int a = redA[sg][ln64 * 4];
#pragma unroll
      for (int j = 1; j < 4; ++j) {
        float v = redM[sg][ln64 * 4 + j]; int aa = redA[sg][ln64 * 4 + j];
        if (v > m || (v == m && aa < a)) { m = v; a = aa; }
      }
      for (int o = 32; o; o >>= 1) {
        float ov = __shfl_xor(m, o); int oa = __shfl_xor(a, o);
        if (ov > m || (ov == m && oa < a)) { m = ov; a = oa; }
      }
      if (ln64 == 0) {
        bM[sg] = m; bA[sg] = a;
        unsigned validb = (m > -1e8f) ? VBIT : 0u;
        unsigned pinfo = (unsigned)a | ((unsigned)fidS[sg] << 10) | validb | (e << 15);
        unsigned long long Aw = (unsigned long long)pinfo |
                                ((unsigned long long)__float_as_uint(m) << 32);
        __hip_atomic_store(&propA[(step & 1) * (NB * NS) + bs0 + sg], Aw,
                           __ATOMIC_RELAXED, AGENT);
      }
    }
    __syncthreads();
    // deferred lse -> propB
#pragma unroll
    for (int s = 0; s < SPB; ++s) {
      float mv = bM[s];
      redM[s][tid] = expf(cand[s][0] - mv) + expf(cand[s][1] - mv) +
                     expf(cand[s][2] - mv) + expf(cand[s][3] - mv);
    }
    __syncthreads();
    {
      float ps = redM[sg][ln64 * 4];
#pragma unroll
      for (int j = 1; j < 4; ++j) ps += redM[sg][ln64 * 4 + j];
      for (int o = 32; o; o >>= 1) ps += __shfl_xor(ps, o);
      if (ln64 == 0) {
        unsigned long long Bw = (unsigned long long)__float_as_uint(-logf(ps)) |
                                ((unsigned long long)e << 32);
        __hip_atomic_store(&propB[(step & 1) * (NB * NS) + bs0 + sg], Bw,
                           __ATOMIC_RELAXED, AGENT);
      }
    }

    // ---- phase B: poll own slot (fast path), banked winner resolution ----
    {
      int par = (step & 1) * (NB * NS) + b * NS;
      unsigned long long Aw = __hip_atomic_load(&propA[par + tid], __ATOMIC_RELAXED, AGENT);
      if ((((unsigned)Aw >> 15) & 63u) != e) {
        int iters = 0;
        do {
          __builtin_amdgcn_s_sleep(1);
          Aw = __hip_atomic_load(&propA[par + tid], __ATOMIC_RELAXED, AGENT);
          if (++iters > SPINCAP) break;
        } while ((((unsigned)Aw >> 15) & 63u) != e);
      }
      unsigned pi = (unsigned)Aw;
      int pu = pi & 1023;
      unsigned encv = 0;
      if (pi & VBIT) {
        unsigned vb = (unsigned)(Aw >> 32);
        encv = (vb & 0x80000000u) ? ~vb : (vb | 0x80000000u);
        atomicMax(&keyEnc4[bank][pu], encv);
      }
      unsigned long long mm = __ballot((pi & VBIT) != 0);
      if (ln64 == 0) anyL[wv] = (mm != 0ull) ? 1 : 0;
      __syncthreads();
      if (!(anyL[0] | anyL[1] | anyL[2] | anyL[3])) break;  // batch frozen forever
      if (pi & VBIT) {
        if (keyEnc4[bank][pu] == encv) atomicMin(&srvMin4[bank][pu], (unsigned)tid);
        unsigned long long Bw = __hip_atomic_load(&propB[par + tid], __ATOMIC_RELAXED, AGENT);
        if ((unsigned)(Bw >> 32) != e) {
          int iters = 0;
          do {
            __builtin_amdgcn_s_sleep(1);
            Bw = __hip_atomic_load(&propB[par + tid], __ATOMIC_RELAXED, AGENT);
            if (++iters > SPINCAP) break;
          } while ((unsigned)(Bw >> 32) != e);
        }
        atomicAdd(&lsum4[bank][pu], __uint_as_float((unsigned)Bw));
        atomicOr(&fdSh4[bank][pu], 1u << ((pi >> 10) & 15));
      }
      __syncthreads();
#pragma unroll
      for (int it = 0; it < 4; ++it) {
        int u = it * 256 + tid;
        unsigned k0 = keyEnc4[0][u], k1 = keyEnc4[1][u];
        unsigned k2 = keyEnc4[2][u], k3 = keyEnc4[3][u];
        unsigned gmax = max(max(k0, k1), max(k2, k3));
        if (gmax) {
          unsigned win = 0xFFFFFFFFu;
          if (k0 == gmax) win = min(win, srvMin4[0][u]);
          if (k1 == gmax) win = min(win, srvMin4[1][u]);
          if (k2 == gmax) win = min(win, srvMin4[2][u]);
          if (k3 == gmax) win = min(win, srvMin4[3][u]);
          float ls = lsum4[0][u] + lsum4[1][u] + lsum4[2][u] + lsum4[3][u];
          unsigned fda = fdSh4[0][u] | fdSh4[1][u] | fdSh4[2][u] | fdSh4[3][u];
          keyEnc4[0][u] = 0u; keyEnc4[1][u] = 0u; keyEnc4[2][u] = 0u; keyEnc4[3][u] = 0u;
          srvMin4[0][u] = 0xFFFFFFFFu; srvMin4[1][u] = 0xFFFFFFFFu;
          srvMin4[2][u] = 0xFFFFFFFFu; srvMin4[3][u] = 0xFFFFFFFFu;
          lsum4[0][u] = 0.f; lsum4[1][u] = 0.f; lsum4[2][u] = 0.f; lsum4[3][u] = 0.f;
          fdSh4[0][u] = 0u; fdSh4[1][u] = 0u; fdSh4[2][u] = 0u; fdSh4[3][u] = 0u;
          logpv[it] += ls;
          uint32_t pk = upk[it];
          int r = (int)((pk >> 16) & 3) + 1;
          upk[it] = ((pk | fda) & 0xFFFFu) | ((uint32_t)r << 16);
          float rf = (float)r;
          usv[it] = w0 * (rf / 3.0f) + w1 * (fmaxf(3.0f - rf, 0.f) / 3.0f) +
                    ((r == 2) ? w2 : 0.f);
          if ((int)(win >> 2) == g) {
            int sl = win & 3;
            ab |= 1u << (sl * 4 + it);
            float4 c = capS4[sl];        // unique (server,step) winner -> no race
            float4 nc = make_float4(fmaxf(c.x - nax[it], 0.f), fmaxf(c.y - nay[it], 0.f),
                                    fmaxf(c.z - nbx[it], 0.f), fmaxf(c.w - nby[it], 0.f));
            capS4[sl] = nc;
            float4 mv = minv4[sl];
            crS4[sl] = make_float4(nc.x / mv.x, nc.y / mv.y, nc.z / mv.z, nc.w / mv.w);
          }
        }
      }
      __syncthreads();
    }
  }

  // ---- fused outputs: alloc expansion + cap + logp ----
#pragma unroll
  for (int it = 0; it < 4; ++it) {
    int u = it * 256 + tid;
    float4 o;
    o.x = ((ab >> (0 * 4 + it)) & 1u) ? 1.f : 0.f;
    o.y = ((ab >> (1 * 4 + it)) & 1u) ? 1.f : 0.f;
    o.z = ((ab >> (2 * 4 + it)) & 1u) ? 1.f : 0.f;
    o.w = ((ab >> (3 * 4 + it)) & 1u) ? 1.f : 0.f;
    *(float4*)(out + 4 + (size_t)(b * NU + u) * NS + g * 4) = o;
  }
  if (tid < SPB)
    *(float4*)(out + 4 + (size_t)NB * NU * NS + (size_t)(bs0 + tid) * 4) = capS4[tid];
  if (g == 0) {
    float a2 = logpv[0] + logpv[1] + logpv[2] + logpv[3];
    for (int o = 32; o; o >>= 1) a2 += __shfl_xor(a2, o);
    if (ln64 == 0) wredL[wv] = a2;
    __syncthreads();
    if (tid == 0) out[b] = wredL[0] + wredL[1] + wredL[2] + wredL[3];
  }
}

extern "C" void kernel_launch(void* const* d_in, const int* in_sizes, int n_in,
                              void* d_out, int out_size, void* d_ws, size_t ws_size,
                              hipStream_t stream) {
  const float* user_enc = (const float*)d_in[0];
  const float* server_enc = (const float*)d_in[1];
  const float* users = (const float*)d_in[2];
  const float* servers = (const float*)d_in[3];
  const uint8_t* connect = (const uint8_t*)d_in[4];
  const float* fd_onehot = (const float*)d_in[5];
  const float* W_state = (const float*)d_in[6];
  const float* b_state = (const float*)d_in[7];
  const float* W_q = (const float*)d_in[8];
  const float* W_k = (const float*)d_in[9];
  const float* W_us = (const float*)d_in[10];
  const float* fd_alpha = (const float*)d_in[11];
  const float* fd_beta = (const float*)d_in[12];
  const float* score_bias = (const float*)d_in[13];

  char* ws = (char*)d_ws;
  size_t off = 0;
  auto take = [&](size_t bytes) -> void* {
    size_t cur = off;
    off = (off + bytes + 255) & ~(size_t)255;
    return (void*)(ws + cur);
  };
  unsigned long long* propA = (unsigned long long*)take((size_t)2 * NB * NS * 8);  // 16KB
  unsigned long long* propB = (unsigned long long*)take((size_t)2 * NB * NS * 8);  // 16KB (contiguous)
  float* q = (float*)take((size_t)NB * NU * ND * 4);
  float* kb = (float*)take((size_t)NB * NS * ND * 4);
  float* L0T = (float*)take((size_t)NB * NS * NU * 4);
  float* qc = (float*)take((size_t)NB * NU * 4 * 4);
  float* WS_K = (float*)take((size_t)ND * 4 * 4);
  uint32_t* connT = (uint32_t*)take((size_t)NB * NS * 32 * 4);
  float* outp = (float*)d_out;

  // 3 dispatches total
  k_pre1<<<450, 256, 0, stream>>>(connect, W_state, W_k, user_enc, server_enc, b_state,
                                  W_q, connT, WS_K, q, kb, (float4*)propA);
  k_pre2<<<1280, 256, 0, stream>>>(q, WS_K, qc, kb, L0T);
  k_steps4<<<NB * NGRP, 256, 0, stream>>>(
      L0T, qc, users, servers, connT, fd_onehot, W_us, fd_alpha, fd_beta, score_bias,
      propA, propB, outp);
}

// Round 13
// 186.810 us; speedup vs baseline: 1.6957x; 1.2115x over previous
//
#include <hip/hip_runtime.h>
#include <stdint.h>
#include <math.h>

#define NB 4
#define NU 1024
#define NS 256
#define NF 16
#define ND 256
#define NEGV -1000000000.0f
#define VBIT (1u << 14)
#define AGENT __HIP_MEMORY_SCOPE_AGENT
#define SPINCAP (1 << 20)
#define NGRP 64            // blocks per batch
#define SPB 4              // servers per block

// propA[par+bs]: bits0-9 argu | 10-13 fid | 14 valid | 15-20 epoch ; maxv bits << 32
// propB[par+bs]: low32 = -log(sum) bits ; high32 = epoch

// ---- shared 64x64 f32 GEMM body (double-buffered LDS; proven bit-identical) ----
__device__ __forceinline__ void gemm64_body(
    const float* __restrict__ A, const float* __restrict__ Bm, float* __restrict__ C,
    int K, int lda, int ldb, int ldc, const float* __restrict__ biasA, float alpha,
    int m0, int n0, int t,
    float (&As)[2][16][68], float (&Bs)[2][16][68]) {
  int tx = t & 15, ty = t >> 4;
  float acc[4][4];
#pragma unroll
  for (int i = 0; i < 4; i++)
#pragma unroll
    for (int j = 0; j < 4; j++) acc[i][j] = 0.f;
  int lr = t >> 2;
  int kq = (t & 3) * 4;
  {
    float4 av = *(const float4*)(A + (size_t)(m0 + lr) * lda + kq);
    if (biasA) {
      const float* bp = biasA + kq;
      av.x += bp[0]; av.y += bp[1]; av.z += bp[2]; av.w += bp[3];
    }
    As[0][kq + 0][lr] = av.x; As[0][kq + 1][lr] = av.y;
    As[0][kq + 2][lr] = av.z; As[0][kq + 3][lr] = av.w;
    float4 bv = *(const float4*)(Bm + (size_t)(n0 + lr) * ldb + kq);
    Bs[0][kq + 0][lr] = bv.x; Bs[0][kq + 1][lr] = bv.y;
    Bs[0][kq + 2][lr] = bv.z; Bs[0][kq + 3][lr] = bv.w;
  }
  __syncthreads();
  int nt = K >> 4;
  for (int ti = 0; ti < nt; ++ti) {
    int buf = ti & 1;
    float4 av2, bv2;
    bool more = (ti + 1 < nt);
    if (more) {
      int k0 = (ti + 1) << 4;
      av2 = *(const float4*)(A + (size_t)(m0 + lr) * lda + k0 + kq);
      if (biasA) {
        const float* bp = biasA + k0 + kq;
        av2.x += bp[0]; av2.y += bp[1]; av2.z += bp[2]; av2.w += bp[3];
      }
      bv2 = *(const float4*)(Bm + (size_t)(n0 + lr) * ldb + k0 + kq);
    }
#pragma unroll
    for (int k = 0; k < 16; ++k) {
      float4 a = *(const float4*)&As[buf][k][ty * 4];
      float4 bb = *(const float4*)&Bs[buf][k][tx * 4];
      float am[4] = {a.x, a.y, a.z, a.w};
      float bn[4] = {bb.x, bb.y, bb.z, bb.w};
#pragma unroll
      for (int i = 0; i < 4; ++i)
#pragma unroll
        for (int j = 0; j < 4; ++j) acc[i][j] += am[i] * bn[j];
    }
    if (more) {
      __syncthreads();
      int nb = buf ^ 1;
      As[nb][kq + 0][lr] = av2.x; As[nb][kq + 1][lr] = av2.y;
      As[nb][kq + 2][lr] = av2.z; As[nb][kq + 3][lr] = av2.w;
      Bs[nb][kq + 0][lr] = bv2.x; Bs[nb][kq + 1][lr] = bv2.y;
      Bs[nb][kq + 2][lr] = bv2.z; Bs[nb][kq + 3][lr] = bv2.w;
      __syncthreads();
    }
  }
#pragma unroll
  for (int i = 0; i < 4; ++i) {
    float4 o = make_float4(acc[i][0] * alpha, acc[i][1] * alpha,
                           acc[i][2] * alpha, acc[i][3] * alpha);
    *(float4*)(C + (size_t)(m0 + ty * 4 + i) * ldc + n0 + tx * 4) = o;
  }
}

// ---- pre1: transpose(+local dtype detect) | weights | q-gemm | kb-gemm | prop-zero ----
__global__ __launch_bounds__(256) void k_pre1(
    const uint8_t* __restrict__ conn, const float* __restrict__ W_state,
    const float* __restrict__ W_k, const float* __restrict__ user_enc,
    const float* __restrict__ server_enc, const float* __restrict__ b_state,
    const float* __restrict__ W_q,
    uint32_t* __restrict__ connT, float* __restrict__ WS_K,
    float* __restrict__ q, float* __restrict__ kb, float4* __restrict__ propZ) {
  __shared__ float As[2][16][68];
  __shared__ float Bs[2][16][68];
  int blk = blockIdx.x;
  int t = threadIdx.x;
  if (blk < 128) {
    __shared__ unsigned dd[2];
    unsigned c0 = 0, c123 = 0;
    for (int i = t; i < 4096; i += 256) {
      uchar4 v = ((const uchar4*)conn)[i];
      c0 |= v.x; c123 |= (unsigned)(v.y | v.z | v.w);
    }
    if (t == 0) { dd[0] = 0; dd[1] = 0; }
    __syncthreads();
    unsigned long long m0 = __ballot(c0 != 0), m1 = __ballot(c123 != 0);
    if ((t & 63) == 0) {
      if (m0) atomicOr(&dd[0], 1u);
      if (m1) atomicOr(&dd[1], 1u);
    }
    __syncthreads();
    int f = (dd[1] == 0) ? 0 : ((dd[0] == 0) ? 1 : 2);
    int b = blk >> 5, ug = blk & 31;
    int u0 = ug * 32;
    uint8_t* sm = (uint8_t*)&As[0][0][0];   // 8320B < 8704B
#pragma unroll 4
    for (int r = 0; r < 32; ++r) {
      int e = (b * NU + u0 + r) * NS + t;
      bool nz;
      if (f == 0)      nz = ((const int*)conn)[e] != 0;
      else if (f == 1) nz = ((const float*)conn)[e] != 0.0f;
      else             nz = conn[e] != 0;
      sm[r * 260 + t] = nz ? 1 : 0;
    }
    __syncthreads();
    uint32_t word = 0;
#pragma unroll
    for (int j = 0; j < 32; ++j) word |= (uint32_t)sm[j * 260 + t] << j;
    connT[(b * NS + t) * 32 + ug] = word;
  } else if (blk == 128) {
    int d = t;
    const float4* wk4 = (const float4*)(W_k + d * ND);
    const float4* ws4 = (const float4*)W_state;
    float a0 = 0, a1 = 0, a2 = 0, a3 = 0;
    for (int e4 = 0; e4 < ND / 4; ++e4) {
      float4 k4 = wk4[e4];
      float4 w0 = ws4[e4 * 4 + 0];
      a0 += k4.x * w0.x; a1 += k4.x * w0.y; a2 += k4.x * w0.z; a3 += k4.x * w0.w;
      float4 w1 = ws4[e4 * 4 + 1];
      a0 += k4.y * w1.x; a1 += k4.y * w1.y; a2 += k4.y * w1.z; a3 += k4.y * w1.w;
      float4 w2 = ws4[e4 * 4 + 2];
      a0 += k4.z * w2.x; a1 += k4.z * w2.y; a2 += k4.z * w2.z; a3 += k4.z * w2.w;
      float4 w3 = ws4[e4 * 4 + 3];
      a0 += k4.w * w3.x; a1 += k4.w * w3.y; a2 += k4.w * w3.z; a3 += k4.w * w3.w;
    }
    ((float4*)WS_K)[d] = make_float4(a0, a1, a2, a3);
  } else if (blk < 385) {
    int idx = blk - 129;           // q-gemm: M=4096, N=256 -> 64x4 tiles = 256 blocks
    gemm64_body(user_enc, W_q, q, ND, ND, ND, ND, nullptr, 1.f,
                (idx >> 2) * 64, (idx & 3) * 64, t, As, Bs);
  } else if (blk < 449) {
    int idx = blk - 385;           // kb-gemm: M=1024, N=256 -> 16x4 tiles = 64 blocks
    gemm64_body(server_enc, W_k, kb, ND, ND, ND, ND, b_state, 1.f,
                (idx >> 2) * 64, (idx & 3) * 64, t, As, Bs);
  } else {
    float4 z = make_float4(0.f, 0.f, 0.f, 0.f);
    for (int i = t; i < 2048; i += 256) propZ[i] = z;   // propA+propB 32KB contiguous
  }
}

// ---- pre2: qc | L0T-gemm ----
__global__ __launch_bounds__(256) void k_pre2(const float* __restrict__ q,
                                              const float* __restrict__ WS_K,
                                              float* __restrict__ qc,
                                              const float* __restrict__ kb,
                                              float* __restrict__ L0T) {
  __shared__ float As[2][16][68];
  __shared__ float Bs[2][16][68];
  int blk = blockIdx.x;
  int t = threadIdx.x;
  if (blk < 1024) {
    int row = blk * 4 + (t >> 6);
    int ln = t & 63;
    const float* qr = q + (size_t)row * ND;
    float a0 = 0, a1 = 0, a2 = 0, a3 = 0;
    for (int d = ln; d < ND; d += 64) {
      float qv = qr[d];
      float4 w = ((const float4*)WS_K)[d];
      a0 += qv * w.x; a1 += qv * w.y; a2 += qv * w.z; a3 += qv * w.w;
    }
    for (int o = 32; o; o >>= 1) {
      a0 += __shfl_xor(a0, o); a1 += __shfl_xor(a1, o);
      a2 += __shfl_xor(a2, o); a3 += __shfl_xor(a3, o);
    }
    if (ln == 0)
      ((float4*)qc)[row] = make_float4(a0 * 0.0625f, a1 * 0.0625f, a2 * 0.0625f, a3 * 0.0625f);
  } else {
    int idx = blk - 1024;          // L0T: per batch z, M=NS (4 tiles), N=NU (16 tiles)
    int z = idx >> 6;
    int rest = idx & 63;
    int m0 = (rest >> 4) * 64;
    int n0 = (rest & 15) * 64;
    gemm64_body(kb + (size_t)z * NS * ND, q + (size_t)z * NU * ND,
                L0T + (size_t)z * NS * NU, ND, ND, ND, NU, nullptr, 0.0625f,
                m0, n0, t, As, Bs);
  }
}

// ---- the 32-step allocator: 4 servers/block, 64 blocks/batch, 512 threads (8 waves),
//      each thread owns 2 users; epoch-tagged proposals; banked LDS atomics ----
__global__ __launch_bounds__(512) void k_steps4(
    const float* __restrict__ L0T, const float* __restrict__ qc,
    const float* __restrict__ users, const float* __restrict__ servers,
    const uint32_t* __restrict__ connT, const float* __restrict__ fd_onehot,
    const float* __restrict__ W_us, const float* __restrict__ fd_alpha,
    const float* __restrict__ fd_beta, const float* __restrict__ score_bias,
    unsigned long long* __restrict__ propA, unsigned long long* __restrict__ propB,
    float* __restrict__ out) {
  __shared__ float redM[SPB][512];
  __shared__ int redA[SPB][512];
  __shared__ unsigned keyEnc4[4][NU];
  __shared__ unsigned srvMin4[4][NU];
  __shared__ float lsum4[4][NU];
  __shared__ unsigned fdSh4[4][NU];
  __shared__ float4 capS4[SPB];
  __shared__ float4 crS4[SPB];
  __shared__ float4 minv4[SPB];
  __shared__ int fidS[SPB];
  __shared__ float pM[SPB][2];
  __shared__ int pA[SPB][2];
  __shared__ float pS[SPB][2];
  __shared__ float bM[SPB];
  __shared__ float wredL[8];
  __shared__ int anyL[4];

  const int blk = blockIdx.x;
  // XCD-clustered bijection: batch b on XCD residues {2b, 2b+1}
  const int b = (blk & 7) >> 1;
  const int g = ((blk >> 3) << 1) | (blk & 1);
  const int tid = threadIdx.x;
  const int wv = tid >> 6, ln64 = tid & 63;
  const int bs0 = b * NS + g * SPB;
  const int bank = tid & 3;
  const int sW = wv >> 1, part = wv & 1;   // wave-pair reduction mapping

  const float a_ = fd_alpha[0], be_ = fd_beta[0];
  const float t0 = tanhf(be_), t1 = tanhf(a_ + be_);
  const float sb = score_bias[0];
  const float w0 = W_us[0], w1 = W_us[1], w2 = W_us[2];

  if (tid < SPB) {
    int srow = bs0 + tid;
    int f = 0;
    for (int ff = 0; ff < NF; ++ff)
      if (fd_onehot[srow * NF + ff] > 0.5f) { f = ff; break; }
    fidS[tid] = f;
    float4 ic = make_float4(servers[srow * 8 + 3], servers[srow * 8 + 4],
                            servers[srow * 8 + 5], servers[srow * 8 + 6]);
    capS4[tid] = ic;
    float4 mv = make_float4(fmaxf(ic.x, 1e-6f), fmaxf(ic.y, 1e-6f),
                            fmaxf(ic.z, 1e-6f), fmaxf(ic.w, 1e-6f));
    minv4[tid] = mv;
    crS4[tid] = make_float4(ic.x / mv.x, ic.y / mv.y, ic.z / mv.z, ic.w / mv.w);
  }

  // per-thread user state: users tid and tid+512 of batch b
  float qc0[2], qc1[2], qc2[2], qc3[2], nax[2], nay[2], nbx[2], nby[2];
  float L0r[SPB][2];
  uint32_t upk[2] = {0, 0};         // bits 0-15 fdmask, bits 16-17 rc
  float usv[2];
  float logpv[2] = {0, 0};
  uint32_t cb = 0, ab = 0;          // bit (s*2+it)
#pragma unroll
  for (int it = 0; it < 2; ++it) {
    int u = it * 512 + tid, gu = b * NU + u;
    float4 q4 = *(const float4*)(qc + gu * 4);
    qc0[it] = q4.x; qc1[it] = q4.y; qc2[it] = q4.z; qc3[it] = q4.w;
    float2 nA = *(const float2*)(users + gu * 8 + 2);
    float2 nB2 = *(const float2*)(users + gu * 8 + 4);
    nax[it] = nA.x; nay[it] = nA.y; nbx[it] = nB2.x; nby[it] = nB2.y;
    usv[it] = w1;
  }
#pragma unroll
  for (int s = 0; s < SPB; ++s)
#pragma unroll
    for (int it = 0; it < 2; ++it) {
      int u = it * 512 + tid;
      L0r[s][it] = L0T[(size_t)(bs0 + s) * NU + u];
      uint32_t word = connT[(bs0 + s) * 32 + (u >> 5)];
      cb |= ((word >> (u & 31)) & 1u) << (s * 2 + it);
    }
  for (int i = tid; i < 4 * NU; i += 512) {
    (&keyEnc4[0][0])[i] = 0u;
    (&srvMin4[0][0])[i] = 0xFFFFFFFFu;
    (&lsum4[0][0])[i] = 0.f;
    (&fdSh4[0][0])[i] = 0u;
  }
  __syncthreads();

  for (int step = 0; step < 32; ++step) {
    unsigned e = (unsigned)(step + 1);
    // ---- phase A: per-thread best over own 2 users for each of 4 servers ----
    float cand[SPB][2];
#pragma unroll
    for (int s = 0; s < SPB; ++s) {
      float4 c = capS4[s];
      float4 cr = crS4[s];
      int fid = fidS[s];
      float m = NEGV; int a = 0x7fffffff;
#pragma unroll
      for (int it = 0; it < 2; ++it) {
        int u = it * 512 + tid;
        bool el = ((cb >> (s * 2 + it)) & 1u) && !((ab >> (s * 2 + it)) & 1u) &&
                  ((upk[it] & 0x30000u) != 0x30000u) &&
                  c.x >= nax[it] && c.y >= nay[it] && c.z >= nbx[it] && c.w >= nby[it];
        float tt = ((upk[it] >> fid) & 1u) ? t0 : t1;
        float lg = L0r[s][it] + qc0[it] * cr.x + qc1[it] * cr.y + qc2[it] * cr.z +
                   qc3[it] * cr.w + sb + tt + usv[it];
        float cv = el ? lg : NEGV;
        cand[s][it] = cv;
        if (cv > m || (cv == m && u < a)) { m = cv; a = u; }
      }
      redM[s][tid] = m; redA[s][tid] = a;
    }
    __syncthreads();
    // wave-pair reduction: wave wv handles server sW, half `part`
    {
      int base = part * 256 + ln64 * 4;
      float m = redM[sW][base]; int a = redA[sW][base];
#pragma unroll
      for (int j = 1; j < 4; ++j) {
        float v = redM[sW][base + j]; int aa = redA[sW][base + j];
        if (v > m || (v == m && aa < a)) { m = v; a = aa; }
      }
      for (int o = 32; o; o >>= 1) {
        float ov = __shfl_xor(m, o); int oa = __shfl_xor(a, o);
        if (ov > m || (ov == m && oa < a)) { m = ov; a = oa; }
      }
      if (ln64 == 0) { pM[sW][part] = m; pA[sW][part] = a; }
    }
    __syncthreads();
    if (tid < SPB) {
      float m0v = pM[tid][0], m1v = pM[tid][1];
      int a0v = pA[tid][0], a1v = pA[tid][1];
      float m; int a;
      if (m1v > m0v || (m1v == m0v && a1v < a0v)) { m = m1v; a = a1v; }
      else { m = m0v; a = a0v; }
      bM[tid] = m;
      unsigned validb = (m > -1e8f) ? VBIT : 0u;
      unsigned pinfo = (unsigned)a | ((unsigned)fidS[tid] << 10) | validb | (e << 15);
      unsigned long long Aw = (unsigned long long)pinfo |
                              ((unsigned long long)__float_as_uint(m) << 32);
      __hip_atomic_store(&propA[(step & 1) * (NB * NS) + bs0 + tid], Aw,
                         __ATOMIC_RELAXED, AGENT);
    }
    __syncthreads();
    // deferred lse -> propB
#pragma unroll
    for (int s = 0; s < SPB; ++s) {
      float mv = bM[s];
      redM[s][tid] = expf(cand[s][0] - mv) + expf(cand[s][1] - mv);
    }
    __syncthreads();
    {
      int base = part * 256 + ln64 * 4;
      float ps = redM[sW][base] + redM[sW][base + 1] + redM[sW][base + 2] +
                 redM[sW][base + 3];
      for (int o = 32; o; o >>= 1) ps += __shfl_xor(ps, o);
      if (ln64 == 0) pS[sW][part] = ps;
    }
    __syncthreads();
    if (tid < SPB) {
      float ps = pS[tid][0] + pS[tid][1];
      unsigned long long Bw = (unsigned long long)__float_as_uint(-logf(ps)) |
                              ((unsigned long long)e << 32);
      __hip_atomic_store(&propB[(step & 1) * (NB * NS) + bs0 + tid], Bw,
                         __ATOMIC_RELAXED, AGENT);
    }

    // ---- phase B: threads 0-255 poll + banked atomics; all threads consume ----
    {
      int par = (step & 1) * (NB * NS) + b * NS;
      unsigned pi = 0;
      if (tid < 256) {
        unsigned long long Aw = __hip_atomic_load(&propA[par + tid], __ATOMIC_RELAXED, AGENT);
        if ((((unsigned)Aw >> 15) & 63u) != e) {
          int iters = 0;
          do {
            __builtin_amdgcn_s_sleep(1);
            Aw = __hip_atomic_load(&propA[par + tid], __ATOMIC_RELAXED, AGENT);
            if (++iters > SPINCAP) break;
          } while ((((unsigned)Aw >> 15) & 63u) != e);
        }
        pi = (unsigned)Aw;
        int pu = pi & 1023;
        if (pi & VBIT) {
          unsigned vb = (unsigned)(Aw >> 32);
          unsigned encv = (vb & 0x80000000u) ? ~vb : (vb | 0x80000000u);
          atomicMax(&keyEnc4[bank][pu], encv);
          if (keyEnc4[bank][pu] == encv) atomicMin(&srvMin4[bank][pu], (unsigned)tid);
          unsigned long long Bw = __hip_atomic_load(&propB[par + tid], __ATOMIC_RELAXED, AGENT);
          if ((unsigned)(Bw >> 32) != e) {
            int iters = 0;
            do {
              __builtin_amdgcn_s_sleep(1);
              Bw = __hip_atomic_load(&propB[par + tid], __ATOMIC_RELAXED, AGENT);
              if (++iters > SPINCAP) break;
            } while ((unsigned)(Bw >> 32) != e);
          }
          atomicAdd(&lsum4[bank][pu], __uint_as_float((unsigned)Bw));
          atomicOr(&fdSh4[bank][pu], 1u << ((pi >> 10) & 15));
        }
      }
      unsigned long long mm = __ballot((pi & VBIT) != 0);
      if (wv < 4 && ln64 == 0) anyL[wv] = (mm != 0ull) ? 1 : 0;
      __syncthreads();
      if (!(anyL[0] | anyL[1] | anyL[2] | anyL[3])) break;  // batch frozen forever
      // note: keyEnc writes before a break can't happen (break => no valid proposals)
#pragma unroll
      for (int it = 0; it < 2; ++it) {
        int u = it * 512 + tid;
        unsigned k0 = keyEnc4[0][u], k1 = keyEnc4[1][u];
        unsigned k2 = keyEnc4[2][u], k3 = keyEnc4[3][u];
        unsigned gmax = max(max(k0, k1), max(k2, k3));
        if (gmax) {
          unsigned win = 0xFFFFFFFFu;
          if (k0 == gmax) win = min(win, srvMin4[0][u]);
          if (k1 == gmax) win = min(win, srvMin4[1][u]);
          if (k2 == gmax) win = min(win, srvMin4[2][u]);
          if (k3 == gmax) win = min(win, srvMin4[3][u]);
          float ls = lsum4[0][u] + lsum4[1][u] + lsum4[2][u] + lsum4[3][u];
          unsigned fda = fdSh4[0][u] | fdSh4[1][u] | fdSh4[2][u] | fdSh4[3][u];
          keyEnc4[0][u] = 0u; keyEnc4[1][u] = 0u; keyEnc4[2][u] = 0u; keyEnc4[3][u] = 0u;
          srvMin4[0][u] = 0xFFFFFFFFu; srvMin4[1][u] = 0xFFFFFFFFu;
          srvMin4[2][u] = 0xFFFFFFFFu; srvMin4[3][u] = 0xFFFFFFFFu;
          lsum4[0][u] = 0.f; lsum4[1][u] = 0.f; lsum4[2][u] = 0.f; lsum4[3][u] = 0.f;
          fdSh4[0][u] = 0u; fdSh4[1][u] = 0u; fdSh4[2][u] = 0u; fdSh4[3][u] = 0u;
          logpv[it] += ls;
          uint32_t pk = upk[it];
          int r = (int)((pk >> 16) & 3) + 1;
          upk[it] = ((pk | fda) & 0xFFFFu) | ((uint32_t)r << 16);
          float rf = (float)r;
          usv[it] = w0 * (rf / 3.0f) + w1 * (fmaxf(3.0f - rf, 0.f) / 3.0f) +
                    ((r == 2) ? w2 : 0.f);
          if ((int)(win >> 2) == g) {
            int sl = win & 3;
            ab |= 1u << (sl * 2 + it);
            float4 c = capS4[sl];        // unique (server,step) winner -> no race
            float4 nc = make_float4(fmaxf(c.x - nax[it], 0.f), fmaxf(c.y - nay[it], 0.f),
                                    fmaxf(c.z - nbx[it], 0.f), fmaxf(c.w - nby[it], 0.f));
            capS4[sl] = nc;
            float4 mv = minv4[sl];
            crS4[sl] = make_float4(nc.x / mv.x, nc.y / mv.y, nc.z / mv.z, nc.w / mv.w);
          }
        }
      }
      __syncthreads();
    }
  }

  // ---- fused outputs: alloc expansion + cap + logp ----
#pragma unroll
  for (int it = 0; it < 2; ++it) {
    int u = it * 512 + tid;
    float4 o;
    o.x = ((ab >> (0 * 2 + it)) & 1u) ? 1.f : 0.f;
    o.y = ((ab >> (1 * 2 + it)) & 1u) ? 1.f : 0.f;
    o.z = ((ab >> (2 * 2 + it)) & 1u) ? 1.f : 0.f;
    o.w = ((ab >> (3 * 2 + it)) & 1u) ? 1.f : 0.f;
    *(float4*)(out + 4 + (size_t)(b * NU + u) * NS + g * 4) = o;
  }
  if (tid < SPB)
    *(float4*)(out + 4 + (size_t)NB * NU * NS + (size_t)(bs0 + tid) * 4) = capS4[tid];
  if (g == 0) {
    float a2 = logpv[0] + logpv[1];
    for (int o = 32; o; o >>= 1) a2 += __shfl_xor(a2, o);
    if (ln64 == 0) wredL[wv] = a2;
    __syncthreads();
    if (tid == 0)
      out[b] = wredL[0] + wredL[1] + wredL[2] + wredL[3] +
               wredL[4] + wredL[5] + wredL[6] + wredL[7];
  }
}

extern "C" void kernel_launch(void* const* d_in, const int* in_sizes, int n_in,
                              void* d_out, int out_size, void* d_ws, size_t ws_size,
                              hipStream_t stream) {
  const float* user_enc = (const float*)d_in[0];
  const float* server_enc = (const float*)d_in[1];
  const float* users = (const float*)d_in[2];
  const float* servers = (const float*)d_in[3];
  const uint8_t* connect = (const uint8_t*)d_in[4];
  const float* fd_onehot = (const float*)d_in[5];
  const float* W_state = (const float*)d_in[6];
  const float* b_state = (const float*)d_in[7];
  const float* W_q = (const float*)d_in[8];
  const float* W_k = (const float*)d_in[9];
  const float* W_us = (const float*)d_in[10];
  const float* fd_alpha = (const float*)d_in[11];
  const float* fd_beta = (const float*)d_in[12];
  const float* score_bias = (const float*)d_in[13];

  char* ws = (char*)d_ws;
  size_t off = 0;
  auto take = [&](size_t bytes) -> void* {
    size_t cur = off;
    off = (off + bytes + 255) & ~(size_t)255;
    return (void*)(ws + cur);
  };
  unsigned long long* propA = (unsigned long long*)take((size_t)2 * NB * NS * 8);  // 16KB
  unsigned long long* propB = (unsigned long long*)take((size_t)2 * NB * NS * 8);  // 16KB (contiguous)
  float* q = (float*)take((size_t)NB * NU * ND * 4);
  float* kb = (float*)take((size_t)NB * NS * ND * 4);
  float* L0T = (float*)take((size_t)NB * NS * NU * 4);
  float* qc = (float*)take((size_t)NB * NU * 4 * 4);
  float* WS_K = (float*)take((size_t)ND * 4 * 4);
  uint32_t* connT = (uint32_t*)take((size_t)NB * NS * 32 * 4);
  float* outp = (float*)d_out;

  // 3 dispatches total
  k_pre1<<<450, 256, 0, stream>>>(connect, W_state, W_k, user_enc, server_enc, b_state,
                                  W_q, connT, WS_K, q, kb, (float4*)propA);
  k_pre2<<<1280, 256, 0, stream>>>(q, WS_K, qc, kb, L0T);
  k_steps4<<<NB * NGRP, 512, 0, stream>>>(
      L0T, qc, users, servers, connT, fd_onehot, W_us, fd_alpha, fd_beta, score_bias,
      propA, propB, outp);
}

// Round 14
// 186.660 us; speedup vs baseline: 1.6971x; 1.0008x over previous
//
#include <hip/hip_runtime.h>
#include <stdint.h>
#include <math.h>

#define NB 4
#define NU 1024
#define NS 256
#define NF 16
#define ND 256
#define NEGV -1000000000.0f
#define VBIT (1u << 14)
#define AGENT __HIP_MEMORY_SCOPE_AGENT
#define SPINCAP (1 << 20)
#define NGRP 64            // blocks per batch
#define SPB 4              // servers per block

// propA[par+bs]: bits0-9 argu | 10-13 fid | 14 valid | 15-20 epoch ; maxv bits << 32
// propB[par+bs]: low32 = -log(sum) bits ; high32 = epoch

// ---- shared 64x64 f32 GEMM body (double-buffered LDS; proven bit-identical) ----
__device__ __forceinline__ void gemm64_body(
    const float* __restrict__ A, const float* __restrict__ Bm, float* __restrict__ C,
    int K, int lda, int ldb, int ldc, const float* __restrict__ biasA, float alpha,
    int m0, int n0, int t,
    float (&As)[2][16][68], float (&Bs)[2][16][68]) {
  int tx = t & 15, ty = t >> 4;
  float acc[4][4];
#pragma unroll
  for (int i = 0; i < 4; i++)
#pragma unroll
    for (int j = 0; j < 4; j++) acc[i][j] = 0.f;
  int lr = t >> 2;
  int kq = (t & 3) * 4;
  {
    float4 av = *(const float4*)(A + (size_t)(m0 + lr) * lda + kq);
    if (biasA) {
      const float* bp = biasA + kq;
      av.x += bp[0]; av.y += bp[1]; av.z += bp[2]; av.w += bp[3];
    }
    As[0][kq + 0][lr] = av.x; As[0][kq + 1][lr] = av.y;
    As[0][kq + 2][lr] = av.z; As[0][kq + 3][lr] = av.w;
    float4 bv = *(const float4*)(Bm + (size_t)(n0 + lr) * ldb + kq);
    Bs[0][kq + 0][lr] = bv.x; Bs[0][kq + 1][lr] = bv.y;
    Bs[0][kq + 2][lr] = bv.z; Bs[0][kq + 3][lr] = bv.w;
  }
  __syncthreads();
  int nt = K >> 4;
  for (int ti = 0; ti < nt; ++ti) {
    int buf = ti & 1;
    float4 av2, bv2;
    bool more = (ti + 1 < nt);
    if (more) {
      int k0 = (ti + 1) << 4;
      av2 = *(const float4*)(A + (size_t)(m0 + lr) * lda + k0 + kq);
      if (biasA) {
        const float* bp = biasA + k0 + kq;
        av2.x += bp[0]; av2.y += bp[1]; av2.z += bp[2]; av2.w += bp[3];
      }
      bv2 = *(const float4*)(Bm + (size_t)(n0 + lr) * ldb + k0 + kq);
    }
#pragma unroll
    for (int k = 0; k < 16; ++k) {
      float4 a = *(const float4*)&As[buf][k][ty * 4];
      float4 bb = *(const float4*)&Bs[buf][k][tx * 4];
      float am[4] = {a.x, a.y, a.z, a.w};
      float bn[4] = {bb.x, bb.y, bb.z, bb.w};
#pragma unroll
      for (int i = 0; i < 4; ++i)
#pragma unroll
        for (int j = 0; j < 4; ++j) acc[i][j] += am[i] * bn[j];
    }
    if (more) {
      __syncthreads();
      int nb = buf ^ 1;
      As[nb][kq + 0][lr] = av2.x; As[nb][kq + 1][lr] = av2.y;
      As[nb][kq + 2][lr] = av2.z; As[nb][kq + 3][lr] = av2.w;
      Bs[nb][kq + 0][lr] = bv2.x; Bs[nb][kq + 1][lr] = bv2.y;
      Bs[nb][kq + 2][lr] = bv2.z; Bs[nb][kq + 3][lr] = bv2.w;
      __syncthreads();
    }
  }
#pragma unroll
  for (int i = 0; i < 4; ++i) {
    float4 o = make_float4(acc[i][0] * alpha, acc[i][1] * alpha,
                           acc[i][2] * alpha, acc[i][3] * alpha);
    *(float4*)(C + (size_t)(m0 + ty * 4 + i) * ldc + n0 + tx * 4) = o;
  }
}

// ---- pre1: transpose(+local dtype detect) | weights | q-gemm | kb-gemm | prop-zero ----
__global__ __launch_bounds__(256) void k_pre1(
    const uint8_t* __restrict__ conn, const float* __restrict__ W_state,
    const float* __restrict__ W_k, const float* __restrict__ user_enc,
    const float* __restrict__ server_enc, const float* __restrict__ b_state,
    const float* __restrict__ W_q,
    uint32_t* __restrict__ connT, float* __restrict__ WS_K,
    float* __restrict__ q, float* __restrict__ kb, float4* __restrict__ propZ) {
  __shared__ float As[2][16][68];
  __shared__ float Bs[2][16][68];
  int blk = blockIdx.x;
  int t = threadIdx.x;
  if (blk < 128) {
    __shared__ unsigned dd[2];
    unsigned c0 = 0, c123 = 0;
    for (int i = t; i < 4096; i += 256) {
      uchar4 v = ((const uchar4*)conn)[i];
      c0 |= v.x; c123 |= (unsigned)(v.y | v.z | v.w);
    }
    if (t == 0) { dd[0] = 0; dd[1] = 0; }
    __syncthreads();
    unsigned long long m0 = __ballot(c0 != 0), m1 = __ballot(c123 != 0);
    if ((t & 63) == 0) {
      if (m0) atomicOr(&dd[0], 1u);
      if (m1) atomicOr(&dd[1], 1u);
    }
    __syncthreads();
    int f = (dd[1] == 0) ? 0 : ((dd[0] == 0) ? 1 : 2);
    int b = blk >> 5, ug = blk & 31;
    int u0 = ug * 32;
    uint8_t* sm = (uint8_t*)&As[0][0][0];   // 8320B < 8704B
#pragma unroll 4
    for (int r = 0; r < 32; ++r) {
      int e = (b * NU + u0 + r) * NS + t;
      bool nz;
      if (f == 0)      nz = ((const int*)conn)[e] != 0;
      else if (f == 1) nz = ((const float*)conn)[e] != 0.0f;
      else             nz = conn[e] != 0;
      sm[r * 260 + t] = nz ? 1 : 0;
    }
    __syncthreads();
    uint32_t word = 0;
#pragma unroll
    for (int j = 0; j < 32; ++j) word |= (uint32_t)sm[j * 260 + t] << j;
    connT[(b * NS + t) * 32 + ug] = word;
  } else if (blk == 128) {
    int d = t;
    const float4* wk4 = (const float4*)(W_k + d * ND);
    const float4* ws4 = (const float4*)W_state;
    float a0 = 0, a1 = 0, a2 = 0, a3 = 0;
    for (int e4 = 0; e4 < ND / 4; ++e4) {
      float4 k4 = wk4[e4];
      float4 w0 = ws4[e4 * 4 + 0];
      a0 += k4.x * w0.x; a1 += k4.x * w0.y; a2 += k4.x * w0.z; a3 += k4.x * w0.w;
      float4 w1 = ws4[e4 * 4 + 1];
      a0 += k4.y * w1.x; a1 += k4.y * w1.y; a2 += k4.y * w1.z; a3 += k4.y * w1.w;
      float4 w2 = ws4[e4 * 4 + 2];
      a0 += k4.z * w2.x; a1 += k4.z * w2.y; a2 += k4.z * w2.z; a3 += k4.z * w2.w;
      float4 w3 = ws4[e4 * 4 + 3];
      a0 += k4.w * w3.x; a1 += k4.w * w3.y; a2 += k4.w * w3.z; a3 += k4.w * w3.w;
    }
    ((float4*)WS_K)[d] = make_float4(a0, a1, a2, a3);
  } else if (blk < 385) {
    int idx = blk - 129;           // q-gemm: M=4096, N=256 -> 64x4 tiles = 256 blocks
    gemm64_body(user_enc, W_q, q, ND, ND, ND, ND, nullptr, 1.f,
                (idx >> 2) * 64, (idx & 3) * 64, t, As, Bs);
  } else if (blk < 449) {
    int idx = blk - 385;           // kb-gemm: M=1024, N=256 -> 16x4 tiles = 64 blocks
    gemm64_body(server_enc, W_k, kb, ND, ND, ND, ND, b_state, 1.f,
                (idx >> 2) * 64, (idx & 3) * 64, t, As, Bs);
  } else {
    float4 z = make_float4(0.f, 0.f, 0.f, 0.f);
    for (int i = t; i < 2048; i += 256) propZ[i] = z;   // propA+propB 32KB contiguous
  }
}

// ---- pre2: qc | L0T-gemm ----
__global__ __launch_bounds__(256) void k_pre2(const float* __restrict__ q,
                                              const float* __restrict__ WS_K,
                                              float* __restrict__ qc,
                                              const float* __restrict__ kb,
                                              float* __restrict__ L0T) {
  __shared__ float As[2][16][68];
  __shared__ float Bs[2][16][68];
  int blk = blockIdx.x;
  int t = threadIdx.x;
  if (blk < 1024) {
    int row = blk * 4 + (t >> 6);
    int ln = t & 63;
    const float* qr = q + (size_t)row * ND;
    float a0 = 0, a1 = 0, a2 = 0, a3 = 0;
    for (int d = ln; d < ND; d += 64) {
      float qv = qr[d];
      float4 w = ((const float4*)WS_K)[d];
      a0 += qv * w.x; a1 += qv * w.y; a2 += qv * w.z; a3 += qv * w.w;
    }
    for (int o = 32; o; o >>= 1) {
      a0 += __shfl_xor(a0, o); a1 += __shfl_xor(a1, o);
      a2 += __shfl_xor(a2, o); a3 += __shfl_xor(a3, o);
    }
    if (ln == 0)
      ((float4*)qc)[row] = make_float4(a0 * 0.0625f, a1 * 0.0625f, a2 * 0.0625f, a3 * 0.0625f);
  } else {
    int idx = blk - 1024;          // L0T: per batch z, M=NS (4 tiles), N=NU (16 tiles)
    int z = idx >> 6;
    int rest = idx & 63;
    int m0 = (rest >> 4) * 64;
    int n0 = (rest & 15) * 64;
    gemm64_body(kb + (size_t)z * NS * ND, q + (size_t)z * NU * ND,
                L0T + (size_t)z * NS * NU, ND, ND, ND, NU, nullptr, 0.0625f,
                m0, n0, t, As, Bs);
  }
}

// ---- the 32-step allocator: 4 servers/block, 64 blocks/batch, 512 threads (8 waves),
//      each thread owns 2 users; epoch-tagged proposals; banked LDS atomics with
//      race-free two-phase winner resolution (round-12 ordering) ----
__global__ __launch_bounds__(512) void k_steps4(
    const float* __restrict__ L0T, const float* __restrict__ qc,
    const float* __restrict__ users, const float* __restrict__ servers,
    const uint32_t* __restrict__ connT, const float* __restrict__ fd_onehot,
    const float* __restrict__ W_us, const float* __restrict__ fd_alpha,
    const float* __restrict__ fd_beta, const float* __restrict__ score_bias,
    unsigned long long* __restrict__ propA, unsigned long long* __restrict__ propB,
    float* __restrict__ out) {
  __shared__ float redM[SPB][512];
  __shared__ int redA[SPB][512];
  __shared__ unsigned keyEnc4[4][NU];
  __shared__ unsigned srvMin4[4][NU];
  __shared__ float lsum4[4][NU];
  __shared__ unsigned fdSh4[4][NU];
  __shared__ float4 capS4[SPB];
  __shared__ float4 crS4[SPB];
  __shared__ float4 minv4[SPB];
  __shared__ int fidS[SPB];
  __shared__ float pM[SPB][2];
  __shared__ int pA[SPB][2];
  __shared__ float pS[SPB][2];
  __shared__ float bM[SPB];
  __shared__ float wredL[8];
  __shared__ int anyL[4];

  const int blk = blockIdx.x;
  // XCD-clustered bijection: batch b on XCD residues {2b, 2b+1}
  const int b = (blk & 7) >> 1;
  const int g = ((blk >> 3) << 1) | (blk & 1);
  const int tid = threadIdx.x;
  const int wv = tid >> 6, ln64 = tid & 63;
  const int bs0 = b * NS + g * SPB;
  const int bank = tid & 3;
  const int sW = wv >> 1, part = wv & 1;   // wave-pair reduction mapping

  const float a_ = fd_alpha[0], be_ = fd_beta[0];
  const float t0 = tanhf(be_), t1 = tanhf(a_ + be_);
  const float sb = score_bias[0];
  const float w0 = W_us[0], w1 = W_us[1], w2 = W_us[2];

  if (tid < SPB) {
    int srow = bs0 + tid;
    int f = 0;
    for (int ff = 0; ff < NF; ++ff)
      if (fd_onehot[srow * NF + ff] > 0.5f) { f = ff; break; }
    fidS[tid] = f;
    float4 ic = make_float4(servers[srow * 8 + 3], servers[srow * 8 + 4],
                            servers[srow * 8 + 5], servers[srow * 8 + 6]);
    capS4[tid] = ic;
    float4 mv = make_float4(fmaxf(ic.x, 1e-6f), fmaxf(ic.y, 1e-6f),
                            fmaxf(ic.z, 1e-6f), fmaxf(ic.w, 1e-6f));
    minv4[tid] = mv;
    crS4[tid] = make_float4(ic.x / mv.x, ic.y / mv.y, ic.z / mv.z, ic.w / mv.w);
  }

  // per-thread user state: users tid and tid+512 of batch b
  float qc0[2], qc1[2], qc2[2], qc3[2], nax[2], nay[2], nbx[2], nby[2];
  float L0r[SPB][2];
  uint32_t upk[2] = {0, 0};         // bits 0-15 fdmask, bits 16-17 rc
  float usv[2];
  float logpv[2] = {0, 0};
  uint32_t cb = 0, ab = 0;          // bit (s*2+it)
#pragma unroll
  for (int it = 0; it < 2; ++it) {
    int u = it * 512 + tid, gu = b * NU + u;
    float4 q4 = *(const float4*)(qc + gu * 4);
    qc0[it] = q4.x; qc1[it] = q4.y; qc2[it] = q4.z; qc3[it] = q4.w;
    float2 nA = *(const float2*)(users + gu * 8 + 2);
    float2 nB2 = *(const float2*)(users + gu * 8 + 4);
    nax[it] = nA.x; nay[it] = nA.y; nbx[it] = nB2.x; nby[it] = nB2.y;
    usv[it] = w1;
  }
#pragma unroll
  for (int s = 0; s < SPB; ++s)
#pragma unroll
    for (int it = 0; it < 2; ++it) {
      int u = it * 512 + tid;
      L0r[s][it] = L0T[(size_t)(bs0 + s) * NU + u];
      uint32_t word = connT[(bs0 + s) * 32 + (u >> 5)];
      cb |= ((word >> (u & 31)) & 1u) << (s * 2 + it);
    }
  for (int i = tid; i < 4 * NU; i += 512) {
    (&keyEnc4[0][0])[i] = 0u;
    (&srvMin4[0][0])[i] = 0xFFFFFFFFu;
    (&lsum4[0][0])[i] = 0.f;
    (&fdSh4[0][0])[i] = 0u;
  }
  __syncthreads();

  for (int step = 0; step < 32; ++step) {
    unsigned e = (unsigned)(step + 1);
    // ---- phase A: per-thread best over own 2 users for each of 4 servers ----
    float cand[SPB][2];
#pragma unroll
    for (int s = 0; s < SPB; ++s) {
      float4 c = capS4[s];
      float4 cr = crS4[s];
      int fid = fidS[s];
      float m = NEGV; int a = 0x7fffffff;
#pragma unroll
      for (int it = 0; it < 2; ++it) {
        int u = it * 512 + tid;
        bool el = ((cb >> (s * 2 + it)) & 1u) && !((ab >> (s * 2 + it)) & 1u) &&
                  ((upk[it] & 0x30000u) != 0x30000u) &&
                  c.x >= nax[it] && c.y >= nay[it] && c.z >= nbx[it] && c.w >= nby[it];
        float tt = ((upk[it] >> fid) & 1u) ? t0 : t1;
        float lg = L0r[s][it] + qc0[it] * cr.x + qc1[it] * cr.y + qc2[it] * cr.z +
                   qc3[it] * cr.w + sb + tt + usv[it];
        float cv = el ? lg : NEGV;
        cand[s][it] = cv;
        if (cv > m || (cv == m && u < a)) { m = cv; a = u; }
      }
      redM[s][tid] = m; redA[s][tid] = a;
    }
    __syncthreads();
    // wave-pair reduction: wave wv handles server sW, half `part`
    {
      int base = part * 256 + ln64 * 4;
      float m = redM[sW][base]; int a = redA[sW][base];
#pragma unroll
      for (int j = 1; j < 4; ++j) {
        float v = redM[sW][base + j]; int aa = redA[sW][base + j];
        if (v > m || (v == m && aa < a)) { m = v; a = aa; }
      }
      for (int o = 32; o; o >>= 1) {
        float ov = __shfl_xor(m, o); int oa = __shfl_xor(a, o);
        if (ov > m || (ov == m && oa < a)) { m = ov; a = oa; }
      }
      if (ln64 == 0) { pM[sW][part] = m; pA[sW][part] = a; }
    }
    __syncthreads();
    if (tid < SPB) {
      float m0v = pM[tid][0], m1v = pM[tid][1];
      int a0v = pA[tid][0], a1v = pA[tid][1];
      float m; int a;
      if (m1v > m0v || (m1v == m0v && a1v < a0v)) { m = m1v; a = a1v; }
      else { m = m0v; a = a0v; }
      bM[tid] = m;
      unsigned validb = (m > -1e8f) ? VBIT : 0u;
      unsigned pinfo = (unsigned)a | ((unsigned)fidS[tid] << 10) | validb | (e << 15);
      unsigned long long Aw = (unsigned long long)pinfo |
                              ((unsigned long long)__float_as_uint(m) << 32);
      __hip_atomic_store(&propA[(step & 1) * (NB * NS) + bs0 + tid], Aw,
                         __ATOMIC_RELAXED, AGENT);
    }
    __syncthreads();
    // deferred lse -> propB
#pragma unroll
    for (int s = 0; s < SPB; ++s) {
      float mv = bM[s];
      redM[s][tid] = expf(cand[s][0] - mv) + expf(cand[s][1] - mv);
    }
    __syncthreads();
    {
      int base = part * 256 + ln64 * 4;
      float ps = redM[sW][base] + redM[sW][base + 1] + redM[sW][base + 2] +
                 redM[sW][base + 3];
      for (int o = 32; o; o >>= 1) ps += __shfl_xor(ps, o);
      if (ln64 == 0) pS[sW][part] = ps;
    }
    __syncthreads();
    if (tid < SPB) {
      float ps = pS[tid][0] + pS[tid][1];
      unsigned long long Bw = (unsigned long long)__float_as_uint(-logf(ps)) |
                              ((unsigned long long)e << 32);
      __hip_atomic_store(&propB[(step & 1) * (NB * NS) + bs0 + tid], Bw,
                         __ATOMIC_RELAXED, AGENT);
    }

    // ---- phase B: two-phase race-free winner resolution (round-12 ordering) ----
    {
      int par = (step & 1) * (NB * NS) + b * NS;
      unsigned pi = 0;
      unsigned encv = 0;
      int pu = 0;
      if (tid < 256) {
        unsigned long long Aw = __hip_atomic_load(&propA[par + tid], __ATOMIC_RELAXED, AGENT);
        if ((((unsigned)Aw >> 15) & 63u) != e) {
          int iters = 0;
          do {
            __builtin_amdgcn_s_sleep(1);
            Aw = __hip_atomic_load(&propA[par + tid], __ATOMIC_RELAXED, AGENT);
            if (++iters > SPINCAP) break;
          } while ((((unsigned)Aw >> 15) & 63u) != e);
        }
        pi = (unsigned)Aw;
        pu = pi & 1023;
        if (pi & VBIT) {
          unsigned vb = (unsigned)(Aw >> 32);
          encv = (vb & 0x80000000u) ? ~vb : (vb | 0x80000000u);
          atomicMax(&keyEnc4[bank][pu], encv);     // phase 1: max only
        }
      }
      unsigned long long mm = __ballot((pi & VBIT) != 0);
      if (wv < 4 && ln64 == 0) anyL[wv] = (mm != 0ull) ? 1 : 0;
      __syncthreads();                              // all atomicMax complete
      if (!(anyL[0] | anyL[1] | anyL[2] | anyL[3])) break;  // batch frozen forever
      if ((tid < 256) && (pi & VBIT)) {
        if (keyEnc4[bank][pu] == encv)              // phase 2: bank max is final
          atomicMin(&srvMin4[bank][pu], (unsigned)tid);
        unsigned long long Bw = __hip_atomic_load(&propB[par + tid], __ATOMIC_RELAXED, AGENT);
        if ((unsigned)(Bw >> 32) != e) {
          int iters = 0;
          do {
            __builtin_amdgcn_s_sleep(1);
            Bw = __hip_atomic_load(&propB[par + tid], __ATOMIC_RELAXED, AGENT);
            if (++iters > SPINCAP) break;
          } while ((unsigned)(Bw >> 32) != e);
        }
        atomicAdd(&lsum4[bank][pu], __uint_as_float((unsigned)Bw));
        atomicOr(&fdSh4[bank][pu], 1u << ((pi >> 10) & 15));
      }
      __syncthreads();                              // all min/add/or complete
#pragma unroll
      for (int it = 0; it < 2; ++it) {
        int u = it * 512 + tid;
        unsigned k0 = keyEnc4[0][u], k1 = keyEnc4[1][u];
        unsigned k2 = keyEnc4[2][u], k3 = keyEnc4[3][u];
        unsigned gmax = max(max(k0, k1), max(k2, k3));
        if (gmax) {
          unsigned win = 0xFFFFFFFFu;
          if (k0 == gmax) win = min(win, srvMin4[0][u]);
          if (k1 == gmax) win = min(win, srvMin4[1][u]);
          if (k2 == gmax) win = min(win, srvMin4[2][u]);
          if (k3 == gmax) win = min(win, srvMin4[3][u]);
          float ls = lsum4[0][u] + lsum4[1][u] + lsum4[2][u] + lsum4[3][u];
          unsigned fda = fdSh4[0][u] | fdSh4[1][u] | fdSh4[2][u] | fdSh4[3][u];
          keyEnc4[0][u] = 0u; keyEnc4[1][u] = 0u; keyEnc4[2][u] = 0u; keyEnc4[3][u] = 0u;
          srvMin4[0][u] = 0xFFFFFFFFu; srvMin4[1][u] = 0xFFFFFFFFu;
          srvMin4[2][u] = 0xFFFFFFFFu; srvMin4[3][u] = 0xFFFFFFFFu;
          lsum4[0][u] = 0.f; lsum4[1][u] = 0.f; lsum4[2][u] = 0.f; lsum4[3][u] = 0.f;
          fdSh4[0][u] = 0u; fdSh4[1][u] = 0u; fdSh4[2][u] = 0u; fdSh4[3][u] = 0u;
          logpv[it] += ls;
          uint32_t pk = upk[it];
          int r = (int)((pk >> 16) & 3) + 1;
          upk[it] = ((pk | fda) & 0xFFFFu) | ((uint32_t)r << 16);
          float rf = (float)r;
          usv[it] = w0 * (rf / 3.0f) + w1 * (fmaxf(3.0f - rf, 0.f) / 3.0f) +
                    ((r == 2) ? w2 : 0.f);
          if ((int)(win >> 2) == g) {
            int sl = win & 3;
            ab |= 1u << (sl * 2 + it);
            float4 c = capS4[sl];        // unique (server,step) winner -> no race
            float4 nc = make_float4(fmaxf(c.x - nax[it], 0.f), fmaxf(c.y - nay[it], 0.f),
                                    fmaxf(c.z - nbx[it], 0.f), fmaxf(c.w - nby[it], 0.f));
            capS4[sl] = nc;
            float4 mv = minv4[sl];
            crS4[sl] = make_float4(nc.x / mv.x, nc.y / mv.y, nc.z / mv.z, nc.w / mv.w);
          }
        }
      }
      __syncthreads();
    }
  }

  // ---- fused outputs: alloc expansion + cap + logp ----
#pragma unroll
  for (int it = 0; it < 2; ++it) {
    int u = it * 512 + tid;
    float4 o;
    o.x = ((ab >> (0 * 2 + it)) & 1u) ? 1.f : 0.f;
    o.y = ((ab >> (1 * 2 + it)) & 1u) ? 1.f : 0.f;
    o.z = ((ab >> (2 * 2 + it)) & 1u) ? 1.f : 0.f;
    o.w = ((ab >> (3 * 2 + it)) & 1u) ? 1.f : 0.f;
    *(float4*)(out + 4 + (size_t)(b * NU + u) * NS + g * 4) = o;
  }
  if (tid < SPB)
    *(float4*)(out + 4 + (size_t)NB * NU * NS + (size_t)(bs0 + tid) * 4) = capS4[tid];
  if (g == 0) {
    float a2 = logpv[0] + logpv[1];
    for (int o = 32; o; o >>= 1) a2 += __shfl_xor(a2, o);
    if (ln64 == 0) wredL[wv] = a2;
    __syncthreads();
    if (tid == 0)
      out[b] = wredL[0] + wredL[1] + wredL[2] + wredL[3] +
               wredL[4] + wredL[5] + wredL[6] + wredL[7];
  }
}

extern "C" void kernel_launch(void* const* d_in, const int* in_sizes, int n_in,
                              void* d_out, int out_size, void* d_ws, size_t ws_size,
                              hipStream_t stream) {
  const float* user_enc = (const float*)d_in[0];
  const float* server_enc = (const float*)d_in[1];
  const float* users = (const float*)d_in[2];
  const float* servers = (const float*)d_in[3];
  const uint8_t* connect = (const uint8_t*)d_in[4];
  const float* fd_onehot = (const float*)d_in[5];
  const float* W_state = (const float*)d_in[6];
  const float* b_state = (const float*)d_in[7];
  const float* W_q = (const float*)d_in[8];
  const float* W_k = (const float*)d_in[9];
  const float* W_us = (const float*)d_in[10];
  const float* fd_alpha = (const float*)d_in[11];
  const float* fd_beta = (const float*)d_in[12];
  const float* score_bias = (const float*)d_in[13];

  char* ws = (char*)d_ws;
  size_t off = 0;
  auto take = [&](size_t bytes) -> void* {
    size_t cur = off;
    off = (off + bytes + 255) & ~(size_t)255;
    return (void*)(ws + cur);
  };
  unsigned long long* propA = (unsigned long long*)take((size_t)2 * NB * NS * 8);  // 16KB
  unsigned long long* propB = (unsigned long long*)take((size_t)2 * NB * NS * 8);  // 16KB (contiguous)
  float* q = (float*)take((size_t)NB * NU * ND * 4);
  float* kb = (float*)take((size_t)NB * NS * ND * 4);
  float* L0T = (float*)take((size_t)NB * NS * NU * 4);
  float* qc = (float*)take((size_t)NB * NU * 4 * 4);
  float* WS_K = (float*)take((size_t)ND * 4 * 4);
  uint32_t* connT = (uint32_t*)take((size_t)NB * NS * 32 * 4);
  float* outp = (float*)d_out;

  // 3 dispatches total
  k_pre1<<<450, 256, 0, stream>>>(connect, W_state, W_k, user_enc, server_enc, b_state,
                                  W_q, connT, WS_K, q, kb, (float4*)propA);
  k_pre2<<<1280, 256, 0, stream>>>(q, WS_K, qc, kb, L0T);
  k_steps4<<<NB * NGRP, 512, 0, stream>>>(
      L0T, qc, users, servers, connT, fd_onehot, W_us, fd_alpha, fd_beta, score_bias,
      propA, propB, outp);
}

// Round 15
// 184.739 us; speedup vs baseline: 1.7147x; 1.0104x over previous
//
#include <hip/hip_runtime.h>
#include <stdint.h>
#include <math.h>

#define NB 4
#define NU 1024
#define NS 256
#define NF 16
#define ND 256
#define NEGV -1000000000.0f
#define VBIT (1u << 14)
#define AGENT __HIP_MEMORY_SCOPE_AGENT
#define SPINCAP (1 << 20)
#define NGRP 64            // blocks per batch
#define SPB 4              // servers per block
#define NT 1024            // threads per step-block (16 waves)

// propA[par+bs]: bits0-9 argu | 10-13 fid | 14 valid | 15-20 epoch ; maxv bits << 32
// propB[par+bs]: low32 = -log(sum) bits ; high32 = epoch

// ---- shared 64x64 f32 GEMM body (double-buffered LDS; proven bit-identical) ----
__device__ __forceinline__ void gemm64_body(
    const float* __restrict__ A, const float* __restrict__ Bm, float* __restrict__ C,
    int K, int lda, int ldb, int ldc, const float* __restrict__ biasA, float alpha,
    int m0, int n0, int t,
    float (&As)[2][16][68], float (&Bs)[2][16][68]) {
  int tx = t & 15, ty = t >> 4;
  float acc[4][4];
#pragma unroll
  for (int i = 0; i < 4; i++)
#pragma unroll
    for (int j = 0; j < 4; j++) acc[i][j] = 0.f;
  int lr = t >> 2;
  int kq = (t & 3) * 4;
  {
    float4 av = *(const float4*)(A + (size_t)(m0 + lr) * lda + kq);
    if (biasA) {
      const float* bp = biasA + kq;
      av.x += bp[0]; av.y += bp[1]; av.z += bp[2]; av.w += bp[3];
    }
    As[0][kq + 0][lr] = av.x; As[0][kq + 1][lr] = av.y;
    As[0][kq + 2][lr] = av.z; As[0][kq + 3][lr] = av.w;
    float4 bv = *(const float4*)(Bm + (size_t)(n0 + lr) * ldb + kq);
    Bs[0][kq + 0][lr] = bv.x; Bs[0][kq + 1][lr] = bv.y;
    Bs[0][kq + 2][lr] = bv.z; Bs[0][kq + 3][lr] = bv.w;
  }
  __syncthreads();
  int nt = K >> 4;
  for (int ti = 0; ti < nt; ++ti) {
    int buf = ti & 1;
    float4 av2, bv2;
    bool more = (ti + 1 < nt);
    if (more) {
      int k0 = (ti + 1) << 4;
      av2 = *(const float4*)(A + (size_t)(m0 + lr) * lda + k0 + kq);
      if (biasA) {
        const float* bp = biasA + k0 + kq;
        av2.x += bp[0]; av2.y += bp[1]; av2.z += bp[2]; av2.w += bp[3];
      }
      bv2 = *(const float4*)(Bm + (size_t)(n0 + lr) * ldb + k0 + kq);
    }
#pragma unroll
    for (int k = 0; k < 16; ++k) {
      float4 a = *(const float4*)&As[buf][k][ty * 4];
      float4 bb = *(const float4*)&Bs[buf][k][tx * 4];
      float am[4] = {a.x, a.y, a.z, a.w};
      float bn[4] = {bb.x, bb.y, bb.z, bb.w};
#pragma unroll
      for (int i = 0; i < 4; ++i)
#pragma unroll
        for (int j = 0; j < 4; ++j) acc[i][j] += am[i] * bn[j];
    }
    if (more) {
      __syncthreads();
      int nb = buf ^ 1;
      As[nb][kq + 0][lr] = av2.x; As[nb][kq + 1][lr] = av2.y;
      As[nb][kq + 2][lr] = av2.z; As[nb][kq + 3][lr] = av2.w;
      Bs[nb][kq + 0][lr] = bv2.x; Bs[nb][kq + 1][lr] = bv2.y;
      Bs[nb][kq + 2][lr] = bv2.z; Bs[nb][kq + 3][lr] = bv2.w;
      __syncthreads();
    }
  }
#pragma unroll
  for (int i = 0; i < 4; ++i) {
    float4 o = make_float4(acc[i][0] * alpha, acc[i][1] * alpha,
                           acc[i][2] * alpha, acc[i][3] * alpha);
    *(float4*)(C + (size_t)(m0 + ty * 4 + i) * ldc + n0 + tx * 4) = o;
  }
}

// ---- pre1: transpose(+local dtype detect) | weights | q-gemm | kb-gemm | prop-zero ----
__global__ __launch_bounds__(256) void k_pre1(
    const uint8_t* __restrict__ conn, const float* __restrict__ W_state,
    const float* __restrict__ W_k, const float* __restrict__ user_enc,
    const float* __restrict__ server_enc, const float* __restrict__ b_state,
    const float* __restrict__ W_q,
    uint32_t* __restrict__ connT, float* __restrict__ WS_K,
    float* __restrict__ q, float* __restrict__ kb, float4* __restrict__ propZ) {
  __shared__ float As[2][16][68];
  __shared__ float Bs[2][16][68];
  int blk = blockIdx.x;
  int t = threadIdx.x;
  if (blk < 128) {
    __shared__ unsigned dd[2];
    unsigned c0 = 0, c123 = 0;
    for (int i = t; i < 4096; i += 256) {
      uchar4 v = ((const uchar4*)conn)[i];
      c0 |= v.x; c123 |= (unsigned)(v.y | v.z | v.w);
    }
    if (t == 0) { dd[0] = 0; dd[1] = 0; }
    __syncthreads();
    unsigned long long m0 = __ballot(c0 != 0), m1 = __ballot(c123 != 0);
    if ((t & 63) == 0) {
      if (m0) atomicOr(&dd[0], 1u);
      if (m1) atomicOr(&dd[1], 1u);
    }
    __syncthreads();
    int f = (dd[1] == 0) ? 0 : ((dd[0] == 0) ? 1 : 2);
    int b = blk >> 5, ug = blk & 31;
    int u0 = ug * 32;
    uint8_t* sm = (uint8_t*)&As[0][0][0];   // 8320B < 8704B
#pragma unroll 4
    for (int r = 0; r < 32; ++r) {
      int e = (b * NU + u0 + r) * NS + t;
      bool nz;
      if (f == 0)      nz = ((const int*)conn)[e] != 0;
      else if (f == 1) nz = ((const float*)conn)[e] != 0.0f;
      else             nz = conn[e] != 0;
      sm[r * 260 + t] = nz ? 1 : 0;
    }
    __syncthreads();
    uint32_t word = 0;
#pragma unroll
    for (int j = 0; j < 32; ++j) word |= (uint32_t)sm[j * 260 + t] << j;
    connT[(b * NS + t) * 32 + ug] = word;
  } else if (blk == 128) {
    int d = t;
    const float4* wk4 = (const float4*)(W_k + d * ND);
    const float4* ws4 = (const float4*)W_state;
    float a0 = 0, a1 = 0, a2 = 0, a3 = 0;
    for (int e4 = 0; e4 < ND / 4; ++e4) {
      float4 k4 = wk4[e4];
      float4 w0 = ws4[e4 * 4 + 0];
      a0 += k4.x * w0.x; a1 += k4.x * w0.y; a2 += k4.x * w0.z; a3 += k4.x * w0.w;
      float4 w1 = ws4[e4 * 4 + 1];
      a0 += k4.y * w1.x; a1 += k4.y * w1.y; a2 += k4.y * w1.z; a3 += k4.y * w1.w;
      float4 w2 = ws4[e4 * 4 + 2];
      a0 += k4.z * w2.x; a1 += k4.z * w2.y; a2 += k4.z * w2.z; a3 += k4.z * w2.w;
      float4 w3 = ws4[e4 * 4 + 3];
      a0 += k4.w * w3.x; a1 += k4.w * w3.y; a2 += k4.w * w3.z; a3 += k4.w * w3.w;
    }
    ((float4*)WS_K)[d] = make_float4(a0, a1, a2, a3);
  } else if (blk < 385) {
    int idx = blk - 129;           // q-gemm: M=4096, N=256 -> 64x4 tiles = 256 blocks
    gemm64_body(user_enc, W_q, q, ND, ND, ND, ND, nullptr, 1.f,
                (idx >> 2) * 64, (idx & 3) * 64, t, As, Bs);
  } else if (blk < 449) {
    int idx = blk - 385;           // kb-gemm: M=1024, N=256 -> 16x4 tiles = 64 blocks
    gemm64_body(server_enc, W_k, kb, ND, ND, ND, ND, b_state, 1.f,
                (idx >> 2) * 64, (idx & 3) * 64, t, As, Bs);
  } else {
    float4 z = make_float4(0.f, 0.f, 0.f, 0.f);
    for (int i = t; i < 2048; i += 256) propZ[i] = z;   // propA+propB 32KB contiguous
  }
}

// ---- pre2: qc | L0T-gemm ----
__global__ __launch_bounds__(256) void k_pre2(const float* __restrict__ q,
                                              const float* __restrict__ WS_K,
                                              float* __restrict__ qc,
                                              const float* __restrict__ kb,
                                              float* __restrict__ L0T) {
  __shared__ float As[2][16][68];
  __shared__ float Bs[2][16][68];
  int blk = blockIdx.x;
  int t = threadIdx.x;
  if (blk < 1024) {
    int row = blk * 4 + (t >> 6);
    int ln = t & 63;
    const float* qr = q + (size_t)row * ND;
    float a0 = 0, a1 = 0, a2 = 0, a3 = 0;
    for (int d = ln; d < ND; d += 64) {
      float qv = qr[d];
      float4 w = ((const float4*)WS_K)[d];
      a0 += qv * w.x; a1 += qv * w.y; a2 += qv * w.z; a3 += qv * w.w;
    }
    for (int o = 32; o; o >>= 1) {
      a0 += __shfl_xor(a0, o); a1 += __shfl_xor(a1, o);
      a2 += __shfl_xor(a2, o); a3 += __shfl_xor(a3, o);
    }
    if (ln == 0)
      ((float4*)qc)[row] = make_float4(a0 * 0.0625f, a1 * 0.0625f, a2 * 0.0625f, a3 * 0.0625f);
  } else {
    int idx = blk - 1024;          // L0T: per batch z, M=NS (4 tiles), N=NU (16 tiles)
    int z = idx >> 6;
    int rest = idx & 63;
    int m0 = (rest >> 4) * 64;
    int n0 = (rest & 15) * 64;
    gemm64_body(kb + (size_t)z * NS * ND, q + (size_t)z * NU * ND,
                L0T + (size_t)z * NS * NU, ND, ND, ND, NU, nullptr, 0.0625f,
                m0, n0, t, As, Bs);
  }
}

// ---- the 32-step allocator: 4 servers/block, 64 blocks/batch, 1024 threads (16 waves),
//      each thread owns 1 user; epoch-tagged proposals; banked LDS atomics;
//      race-free two-phase winner resolution ----
__global__ __launch_bounds__(NT) void k_steps4(
    const float* __restrict__ L0T, const float* __restrict__ qc,
    const float* __restrict__ users, const float* __restrict__ servers,
    const uint32_t* __restrict__ connT, const float* __restrict__ fd_onehot,
    const float* __restrict__ W_us, const float* __restrict__ fd_alpha,
    const float* __restrict__ fd_beta, const float* __restrict__ score_bias,
    unsigned long long* __restrict__ propA, unsigned long long* __restrict__ propB,
    float* __restrict__ out) {
  __shared__ float redM[SPB][NT];
  __shared__ int redA[SPB][NT];
  __shared__ unsigned keyEnc4[4][NU];
  __shared__ unsigned srvMin4[4][NU];
  __shared__ float lsum4[4][NU];
  __shared__ unsigned fdSh4[4][NU];
  __shared__ float4 capS4[SPB];
  __shared__ float4 crS4[SPB];
  __shared__ float4 minv4[SPB];
  __shared__ int fidS[SPB];
  __shared__ float pM[SPB][4];
  __shared__ int pA[SPB][4];
  __shared__ float pS[SPB][4];
  __shared__ float bM[SPB];
  __shared__ float wredL[16];
  __shared__ int anyL[4];

  const int blk = blockIdx.x;
  // XCD-clustered bijection: batch b on XCD residues {2b, 2b+1}
  const int b = (blk & 7) >> 1;
  const int g = ((blk >> 3) << 1) | (blk & 1);
  const int tid = threadIdx.x;
  const int wv = tid >> 6, ln64 = tid & 63;
  const int bs0 = b * NS + g * SPB;
  const int bank = tid & 3;
  const int sW = wv >> 2, part = wv & 3;   // wave->server/quarter reduction mapping

  const float a_ = fd_alpha[0], be_ = fd_beta[0];
  const float t0 = tanhf(be_), t1 = tanhf(a_ + be_);
  const float sb = score_bias[0];
  const float w0 = W_us[0], w1 = W_us[1], w2 = W_us[2];

  if (tid < SPB) {
    int srow = bs0 + tid;
    int f = 0;
    for (int ff = 0; ff < NF; ++ff)
      if (fd_onehot[srow * NF + ff] > 0.5f) { f = ff; break; }
    fidS[tid] = f;
    float4 ic = make_float4(servers[srow * 8 + 3], servers[srow * 8 + 4],
                            servers[srow * 8 + 5], servers[srow * 8 + 6]);
    capS4[tid] = ic;
    float4 mv = make_float4(fmaxf(ic.x, 1e-6f), fmaxf(ic.y, 1e-6f),
                            fmaxf(ic.z, 1e-6f), fmaxf(ic.w, 1e-6f));
    minv4[tid] = mv;
    crS4[tid] = make_float4(ic.x / mv.x, ic.y / mv.y, ic.z / mv.z, ic.w / mv.w);
  }

  // per-thread user state: user u == tid of batch b
  const int gu = b * NU + tid;
  float4 q4 = *(const float4*)(qc + gu * 4);
  float2 nA = *(const float2*)(users + gu * 8 + 2);
  float2 nB2 = *(const float2*)(users + gu * 8 + 4);
  const float nax = nA.x, nay = nA.y, nbx = nB2.x, nby = nB2.y;
  float L0r[SPB];
  uint32_t upk = 0;                 // bits 0-15 fdmask, bits 16-17 rc
  float usv = w1;
  float logpv = 0.f;
  uint32_t cb = 0, ab = 0;          // bit s
#pragma unroll
  for (int s = 0; s < SPB; ++s) {
    L0r[s] = L0T[(size_t)(bs0 + s) * NU + tid];
    uint32_t word = connT[(bs0 + s) * 32 + (tid >> 5)];
    cb |= ((word >> (tid & 31)) & 1u) << s;
  }
  for (int i = tid; i < 4 * NU; i += NT) {
    (&keyEnc4[0][0])[i] = 0u;
    (&srvMin4[0][0])[i] = 0xFFFFFFFFu;
    (&lsum4[0][0])[i] = 0.f;
    (&fdSh4[0][0])[i] = 0u;
  }
  __syncthreads();

  for (int step = 0; step < 32; ++step) {
    unsigned e = (unsigned)(step + 1);
    // ---- phase A: per-thread logits for own user x 4 servers ----
    float cand[SPB];
#pragma unroll
    for (int s = 0; s < SPB; ++s) {
      float4 c = capS4[s];
      float4 cr = crS4[s];
      int fid = fidS[s];
      bool el = ((cb >> s) & 1u) && !((ab >> s) & 1u) &&
                ((upk & 0x30000u) != 0x30000u) &&
                c.x >= nax && c.y >= nay && c.z >= nbx && c.w >= nby;
      float tt = ((upk >> fid) & 1u) ? t0 : t1;
      float lg = L0r[s] + q4.x * cr.x + q4.y * cr.y + q4.z * cr.z + q4.w * cr.w +
                 sb + tt + usv;
      float cv = el ? lg : NEGV;
      cand[s] = cv;
      redM[s][tid] = cv;
      redA[s][tid] = (cv > NEGV) ? tid : 0x7fffffff;
    }
    __syncthreads();
    // 16-wave reduction: wave wv handles server sW, quarter part
    {
      int base = part * 256 + ln64 * 4;
      float m = redM[sW][base]; int a = redA[sW][base];
#pragma unroll
      for (int j = 1; j < 4; ++j) {
        float v = redM[sW][base + j]; int aa = redA[sW][base + j];
        if (v > m || (v == m && aa < a)) { m = v; a = aa; }
      }
      for (int o = 32; o; o >>= 1) {
        float ov = __shfl_xor(m, o); int oa = __shfl_xor(a, o);
        if (ov > m || (ov == m && oa < a)) { m = ov; a = oa; }
      }
      if (ln64 == 0) { pM[sW][part] = m; pA[sW][part] = a; }
    }
    __syncthreads();
    if (tid < SPB) {
      float m = pM[tid][0]; int a = pA[tid][0];
#pragma unroll
      for (int j = 1; j < 4; ++j) {
        float v = pM[tid][j]; int aa = pA[tid][j];
        if (v > m || (v == m && aa < a)) { m = v; a = aa; }
      }
      bM[tid] = m;
      int au = (a == 0x7fffffff) ? 0 : a;    // argu valid only when VBIT set
      unsigned validb = (m > -1e8f) ? VBIT : 0u;
      unsigned pinfo = (unsigned)au | ((unsigned)fidS[tid] << 10) | validb | (e << 15);
      unsigned long long Aw = (unsigned long long)pinfo |
                              ((unsigned long long)__float_as_uint(m) << 32);
      __hip_atomic_store(&propA[(step & 1) * (NB * NS) + bs0 + tid], Aw,
                         __ATOMIC_RELAXED, AGENT);
    }
    __syncthreads();
    // deferred lse -> propB
#pragma unroll
    for (int s = 0; s < SPB; ++s)
      redM[s][tid] = expf(cand[s] - bM[s]);
    __syncthreads();
    {
      int base = part * 256 + ln64 * 4;
      float ps = redM[sW][base] + redM[sW][base + 1] + redM[sW][base + 2] +
                 redM[sW][base + 3];
      for (int o = 32; o; o >>= 1) ps += __shfl_xor(ps, o);
      if (ln64 == 0) pS[sW][part] = ps;
    }
    __syncthreads();
    if (tid < SPB) {
      float ps = pS[tid][0] + pS[tid][1] + pS[tid][2] + pS[tid][3];
      unsigned long long Bw = (unsigned long long)__float_as_uint(-logf(ps)) |
                              ((unsigned long long)e << 32);
      __hip_atomic_store(&propB[(step & 1) * (NB * NS) + bs0 + tid], Bw,
                         __ATOMIC_RELAXED, AGENT);
    }

    // ---- phase B: two-phase race-free winner resolution ----
    {
      int par = (step & 1) * (NB * NS) + b * NS;
      unsigned pi = 0;
      unsigned encv = 0;
      int pu = 0;
      if (tid < 256) {
        unsigned long long Aw = __hip_atomic_load(&propA[par + tid], __ATOMIC_RELAXED, AGENT);
        if ((((unsigned)Aw >> 15) & 63u) != e) {
          int iters = 0;
          do {
            __builtin_amdgcn_s_sleep(1);
            Aw = __hip_atomic_load(&propA[par + tid], __ATOMIC_RELAXED, AGENT);
            if (++iters > SPINCAP) break;
          } while ((((unsigned)Aw >> 15) & 63u) != e);
        }
        pi = (unsigned)Aw;
        pu = pi & 1023;
        if (pi & VBIT) {
          unsigned vb = (unsigned)(Aw >> 32);
          encv = (vb & 0x80000000u) ? ~vb : (vb | 0x80000000u);
          atomicMax(&keyEnc4[bank][pu], encv);     // phase 1: max only
        }
      }
      unsigned long long mm = __ballot((pi & VBIT) != 0);
      if (wv < 4 && ln64 == 0) anyL[wv] = (mm != 0ull) ? 1 : 0;
      __syncthreads();                              // all atomicMax complete
      if (!(anyL[0] | anyL[1] | anyL[2] | anyL[3])) break;  // batch frozen forever
      if ((tid < 256) && (pi & VBIT)) {
        if (keyEnc4[bank][pu] == encv)              // phase 2: bank max is final
          atomicMin(&srvMin4[bank][pu], (unsigned)tid);
        unsigned long long Bw = __hip_atomic_load(&propB[par + tid], __ATOMIC_RELAXED, AGENT);
        if ((unsigned)(Bw >> 32) != e) {
          int iters = 0;
          do {
            __builtin_amdgcn_s_sleep(1);
            Bw = __hip_atomic_load(&propB[par + tid], __ATOMIC_RELAXED, AGENT);
            if (++iters > SPINCAP) break;
          } while ((unsigned)(Bw >> 32) != e);
        }
        atomicAdd(&lsum4[bank][pu], __uint_as_float((unsigned)Bw));
        atomicOr(&fdSh4[bank][pu], 1u << ((pi >> 10) & 15));
      }
      __syncthreads();                              // all min/add/or complete
      {
        int u = tid;
        unsigned k0 = keyEnc4[0][u], k1 = keyEnc4[1][u];
        unsigned k2 = keyEnc4[2][u], k3 = keyEnc4[3][u];
        unsigned gmax = max(max(k0, k1), max(k2, k3));
        if (gmax) {
          unsigned win = 0xFFFFFFFFu;
          if (k0 == gmax) win = min(win, srvMin4[0][u]);
          if (k1 == gmax) win = min(win, srvMin4[1][u]);
          if (k2 == gmax) win = min(win, srvMin4[2][u]);
          if (k3 == gmax) win = min(win, srvMin4[3][u]);
          float ls = lsum4[0][u] + lsum4[1][u] + lsum4[2][u] + lsum4[3][u];
          unsigned fda = fdSh4[0][u] | fdSh4[1][u] | fdSh4[2][u] | fdSh4[3][u];
          keyEnc4[0][u] = 0u; keyEnc4[1][u] = 0u; keyEnc4[2][u] = 0u; keyEnc4[3][u] = 0u;
          srvMin4[0][u] = 0xFFFFFFFFu; srvMin4[1][u] = 0xFFFFFFFFu;
          srvMin4[2][u] = 0xFFFFFFFFu; srvMin4[3][u] = 0xFFFFFFFFu;
          lsum4[0][u] = 0.f; lsum4[1][u] = 0.f; lsum4[2][u] = 0.f; lsum4[3][u] = 0.f;
          fdSh4[0][u] = 0u; fdSh4[1][u] = 0u; fdSh4[2][u] = 0u; fdSh4[3][u] = 0u;
          logpv += ls;
          uint32_t pk = upk;
          int r = (int)((pk >> 16) & 3) + 1;
          upk = ((pk | fda) & 0xFFFFu) | ((uint32_t)r << 16);
          float rf = (float)r;
          usv = w0 * (rf / 3.0f) + w1 * (fmaxf(3.0f - rf, 0.f) / 3.0f) +
                ((r == 2) ? w2 : 0.f);
          if ((int)(win >> 2) == g) {
            int sl = win & 3;
            ab |= 1u << sl;
            float4 c = capS4[sl];        // unique (server,step) winner -> no race
            float4 nc = make_float4(fmaxf(c.x - nax, 0.f), fmaxf(c.y - nay, 0.f),
                                    fmaxf(c.z - nbx, 0.f), fmaxf(c.w - nby, 0.f));
            capS4[sl] = nc;
            float4 mv = minv4[sl];
            crS4[sl] = make_float4(nc.x / mv.x, nc.y / mv.y, nc.z / mv.z, nc.w / mv.w);
          }
        }
      }
      __syncthreads();
    }
  }

  // ---- fused outputs: alloc expansion + cap + logp ----
  {
    float4 o;
    o.x = (ab & 1u) ? 1.f : 0.f;
    o.y = ((ab >> 1) & 1u) ? 1.f : 0.f;
    o.z = ((ab >> 2) & 1u) ? 1.f : 0.f;
    o.w = ((ab >> 3) & 1u) ? 1.f : 0.f;
    *(float4*)(out + 4 + (size_t)(b * NU + tid) * NS + g * 4) = o;
  }
  if (tid < SPB)
    *(float4*)(out + 4 + (size_t)NB * NU * NS + (size_t)(bs0 + tid) * 4) = capS4[tid];
  if (g == 0) {
    float a2 = logpv;
    for (int o = 32; o; o >>= 1) a2 += __shfl_xor(a2, o);
    if (ln64 == 0) wredL[wv] = a2;
    __syncthreads();
    if (tid == 0) {
      float s = 0.f;
#pragma unroll
      for (int i = 0; i < 16; ++i) s += wredL[i];
      out[b] = s;
    }
  }
}

extern "C" void kernel_launch(void* const* d_in, const int* in_sizes, int n_in,
                              void* d_out, int out_size, void* d_ws, size_t ws_size,
                              hipStream_t stream) {
  const float* user_enc = (const float*)d_in[0];
  const float* server_enc = (const float*)d_in[1];
  const float* users = (const float*)d_in[2];
  const float* servers = (const float*)d_in[3];
  const uint8_t* connect = (const uint8_t*)d_in[4];
  const float* fd_onehot = (const float*)d_in[5];
  const float* W_state = (const float*)d_in[6];
  const float* b_state = (const float*)d_in[7];
  const float* W_q = (const float*)d_in[8];
  const float* W_k = (const float*)d_in[9];
  const float* W_us = (const float*)d_in[10];
  const float* fd_alpha = (const float*)d_in[11];
  const float* fd_beta = (const float*)d_in[12];
  const float* score_bias = (const float*)d_in[13];

  char* ws = (char*)d_ws;
  size_t off = 0;
  auto take = [&](size_t bytes) -> void* {
    size_t cur = off;
    off = (off + bytes + 255) & ~(size_t)255;
    return (void*)(ws + cur);
  };
  unsigned long long* propA = (unsigned long long*)take((size_t)2 * NB * NS * 8);  // 16KB
  unsigned long long* propB = (unsigned long long*)take((size_t)2 * NB * NS * 8);  // 16KB (contiguous)
  float* q = (float*)take((size_t)NB * NU * ND * 4);
  float* kb = (float*)take((size_t)NB * NS * ND * 4);
  float* L0T = (float*)take((size_t)NB * NS * NU * 4);
  float* qc = (float*)take((size_t)NB * NU * 4 * 4);
  float* WS_K = (float*)take((size_t)ND * 4 * 4);
  uint32_t* connT = (uint32_t*)take((size_t)NB * NS * 32 * 4);
  float* outp = (float*)d_out;

  // 3 dispatches total
  k_pre1<<<450, 256, 0, stream>>>(connect, W_state, W_k, user_enc, server_enc, b_state,
                                  W_q, connT, WS_K, q, kb, (float4*)propA);
  k_pre2<<<1280, 256, 0, stream>>>(q, WS_K, qc, kb, L0T);
  k_steps4<<<NB * NGRP, NT, 0, stream>>>(
      L0T, qc, users, servers, connT, fd_onehot, W_us, fd_alpha, fd_beta, score_bias,
      propA, propB, outp);
}

// Round 16
// 177.389 us; speedup vs baseline: 1.7858x; 1.0414x over previous
//
#include <hip/hip_runtime.h>
#include <stdint.h>
#include <math.h>

#define NB 4
#define NU 1024
#define NS 256
#define NF 16
#define ND 256
#define NEGV -1000000000.0f
#define VBIT (1u << 14)
#define AGENT __HIP_MEMORY_SCOPE_AGENT
#define SPINCAP (1 << 20)
#define NGRP 64            // blocks per batch
#define SPB 4              // servers per block
#define NT 1024            // threads per step-block (16 waves)

// propA[par+bs]: bits0-9 argu | 10-13 fid | 14 valid | 15-20 epoch ; maxv bits << 32
// propB[par+bs]: low32 = -log(sum) bits ; high32 = epoch

// ---- shared 64x64 f32 GEMM body (double-buffered LDS; proven bit-identical) ----
__device__ __forceinline__ void gemm64_body(
    const float* __restrict__ A, const float* __restrict__ Bm, float* __restrict__ C,
    int K, int lda, int ldb, int ldc, const float* __restrict__ biasA, float alpha,
    int m0, int n0, int t,
    float (&As)[2][16][68], float (&Bs)[2][16][68]) {
  int tx = t & 15, ty = t >> 4;
  float acc[4][4];
#pragma unroll
  for (int i = 0; i < 4; i++)
#pragma unroll
    for (int j = 0; j < 4; j++) acc[i][j] = 0.f;
  int lr = t >> 2;
  int kq = (t & 3) * 4;
  {
    float4 av = *(const float4*)(A + (size_t)(m0 + lr) * lda + kq);
    if (biasA) {
      const float* bp = biasA + kq;
      av.x += bp[0]; av.y += bp[1]; av.z += bp[2]; av.w += bp[3];
    }
    As[0][kq + 0][lr] = av.x; As[0][kq + 1][lr] = av.y;
    As[0][kq + 2][lr] = av.z; As[0][kq + 3][lr] = av.w;
    float4 bv = *(const float4*)(Bm + (size_t)(n0 + lr) * ldb + kq);
    Bs[0][kq + 0][lr] = bv.x; Bs[0][kq + 1][lr] = bv.y;
    Bs[0][kq + 2][lr] = bv.z; Bs[0][kq + 3][lr] = bv.w;
  }
  __syncthreads();
  int nt = K >> 4;
  for (int ti = 0; ti < nt; ++ti) {
    int buf = ti & 1;
    float4 av2, bv2;
    bool more = (ti + 1 < nt);
    if (more) {
      int k0 = (ti + 1) << 4;
      av2 = *(const float4*)(A + (size_t)(m0 + lr) * lda + k0 + kq);
      if (biasA) {
        const float* bp = biasA + k0 + kq;
        av2.x += bp[0]; av2.y += bp[1]; av2.z += bp[2]; av2.w += bp[3];
      }
      bv2 = *(const float4*)(Bm + (size_t)(n0 + lr) * ldb + k0 + kq);
    }
#pragma unroll
    for (int k = 0; k < 16; ++k) {
      float4 a = *(const float4*)&As[buf][k][ty * 4];
      float4 bb = *(const float4*)&Bs[buf][k][tx * 4];
      float am[4] = {a.x, a.y, a.z, a.w};
      float bn[4] = {bb.x, bb.y, bb.z, bb.w};
#pragma unroll
      for (int i = 0; i < 4; ++i)
#pragma unroll
        for (int j = 0; j < 4; ++j) acc[i][j] += am[i] * bn[j];
    }
    if (more) {
      __syncthreads();
      int nb = buf ^ 1;
      As[nb][kq + 0][lr] = av2.x; As[nb][kq + 1][lr] = av2.y;
      As[nb][kq + 2][lr] = av2.z; As[nb][kq + 3][lr] = av2.w;
      Bs[nb][kq + 0][lr] = bv2.x; Bs[nb][kq + 1][lr] = bv2.y;
      Bs[nb][kq + 2][lr] = bv2.z; Bs[nb][kq + 3][lr] = bv2.w;
      __syncthreads();
    }
  }
#pragma unroll
  for (int i = 0; i < 4; ++i) {
    float4 o = make_float4(acc[i][0] * alpha, acc[i][1] * alpha,
                           acc[i][2] * alpha, acc[i][3] * alpha);
    *(float4*)(C + (size_t)(m0 + ty * 4 + i) * ldc + n0 + tx * 4) = o;
  }
}

// ---- pre1: transpose(+local dtype detect) | weights | q-gemm | kb-gemm | prop-zero ----
__global__ __launch_bounds__(256) void k_pre1(
    const uint8_t* __restrict__ conn, const float* __restrict__ W_state,
    const float* __restrict__ W_k, const float* __restrict__ user_enc,
    const float* __restrict__ server_enc, const float* __restrict__ b_state,
    const float* __restrict__ W_q,
    uint32_t* __restrict__ connT, float* __restrict__ WS_K,
    float* __restrict__ q, float* __restrict__ kb, float4* __restrict__ propZ) {
  __shared__ float As[2][16][68];
  __shared__ float Bs[2][16][68];
  int blk = blockIdx.x;
  int t = threadIdx.x;
  if (blk < 128) {
    __shared__ unsigned dd[2];
    unsigned c0 = 0, c123 = 0;
    for (int i = t; i < 4096; i += 256) {
      uchar4 v = ((const uchar4*)conn)[i];
      c0 |= v.x; c123 |= (unsigned)(v.y | v.z | v.w);
    }
    if (t == 0) { dd[0] = 0; dd[1] = 0; }
    __syncthreads();
    unsigned long long m0 = __ballot(c0 != 0), m1 = __ballot(c123 != 0);
    if ((t & 63) == 0) {
      if (m0) atomicOr(&dd[0], 1u);
      if (m1) atomicOr(&dd[1], 1u);
    }
    __syncthreads();
    int f = (dd[1] == 0) ? 0 : ((dd[0] == 0) ? 1 : 2);
    int b = blk >> 5, ug = blk & 31;
    int u0 = ug * 32;
    uint8_t* sm = (uint8_t*)&As[0][0][0];   // 8320B < 8704B
#pragma unroll 4
    for (int r = 0; r < 32; ++r) {
      int e = (b * NU + u0 + r) * NS + t;
      bool nz;
      if (f == 0)      nz = ((const int*)conn)[e] != 0;
      else if (f == 1) nz = ((const float*)conn)[e] != 0.0f;
      else             nz = conn[e] != 0;
      sm[r * 260 + t] = nz ? 1 : 0;
    }
    __syncthreads();
    uint32_t word = 0;
#pragma unroll
    for (int j = 0; j < 32; ++j) word |= (uint32_t)sm[j * 260 + t] << j;
    connT[(b * NS + t) * 32 + ug] = word;
  } else if (blk == 128) {
    int d = t;
    const float4* wk4 = (const float4*)(W_k + d * ND);
    const float4* ws4 = (const float4*)W_state;
    float a0 = 0, a1 = 0, a2 = 0, a3 = 0;
    for (int e4 = 0; e4 < ND / 4; ++e4) {
      float4 k4 = wk4[e4];
      float4 w0 = ws4[e4 * 4 + 0];
      a0 += k4.x * w0.x; a1 += k4.x * w0.y; a2 += k4.x * w0.z; a3 += k4.x * w0.w;
      float4 w1 = ws4[e4 * 4 + 1];
      a0 += k4.y * w1.x; a1 += k4.y * w1.y; a2 += k4.y * w1.z; a3 += k4.y * w1.w;
      float4 w2 = ws4[e4 * 4 + 2];
      a0 += k4.z * w2.x; a1 += k4.z * w2.y; a2 += k4.z * w2.z; a3 += k4.z * w2.w;
      float4 w3 = ws4[e4 * 4 + 3];
      a0 += k4.w * w3.x; a1 += k4.w * w3.y; a2 += k4.w * w3.z; a3 += k4.w * w3.w;
    }
    ((float4*)WS_K)[d] = make_float4(a0, a1, a2, a3);
  } else if (blk < 385) {
    int idx = blk - 129;           // q-gemm: M=4096, N=256 -> 64x4 tiles = 256 blocks
    gemm64_body(user_enc, W_q, q, ND, ND, ND, ND, nullptr, 1.f,
                (idx >> 2) * 64, (idx & 3) * 64, t, As, Bs);
  } else if (blk < 449) {
    int idx = blk - 385;           // kb-gemm: M=1024, N=256 -> 16x4 tiles = 64 blocks
    gemm64_body(server_enc, W_k, kb, ND, ND, ND, ND, b_state, 1.f,
                (idx >> 2) * 64, (idx & 3) * 64, t, As, Bs);
  } else {
    float4 z = make_float4(0.f, 0.f, 0.f, 0.f);
    for (int i = t; i < 2048; i += 256) propZ[i] = z;   // propA+propB 32KB contiguous
  }
}

// ---- pre2: qc | L0T-gemm ----
__global__ __launch_bounds__(256) void k_pre2(const float* __restrict__ q,
                                              const float* __restrict__ WS_K,
                                              float* __restrict__ qc,
                                              const float* __restrict__ kb,
                                              float* __restrict__ L0T) {
  __shared__ float As[2][16][68];
  __shared__ float Bs[2][16][68];
  int blk = blockIdx.x;
  int t = threadIdx.x;
  if (blk < 1024) {
    int row = blk * 4 + (t >> 6);
    int ln = t & 63;
    const float* qr = q + (size_t)row * ND;
    float a0 = 0, a1 = 0, a2 = 0, a3 = 0;
    for (int d = ln; d < ND; d += 64) {
      float qv = qr[d];
      float4 w = ((const float4*)WS_K)[d];
      a0 += qv * w.x; a1 += qv * w.y; a2 += qv * w.z; a3 += qv * w.w;
    }
    for (int o = 32; o; o >>= 1) {
      a0 += __shfl_xor(a0, o); a1 += __shfl_xor(a1, o);
      a2 += __shfl_xor(a2, o); a3 += __shfl_xor(a3, o);
    }
    if (ln == 0)
      ((float4*)qc)[row] = make_float4(a0 * 0.0625f, a1 * 0.0625f, a2 * 0.0625f, a3 * 0.0625f);
  } else {
    int idx = blk - 1024;          // L0T: per batch z, M=NS (4 tiles), N=NU (16 tiles)
    int z = idx >> 6;
    int rest = idx & 63;
    int m0 = (rest >> 4) * 64;
    int n0 = (rest & 15) * 64;
    gemm64_body(kb + (size_t)z * NS * ND, q + (size_t)z * NU * ND,
                L0T + (size_t)z * NS * NU, ND, ND, ND, NU, nullptr, 0.0625f,
                m0, n0, t, As, Bs);
  }
}

// ---- the 32-step allocator: 4 servers/block, 64 blocks/batch, 1024 threads,
//      6 barriers/step, single propA poll (propB consumed one step deferred) ----
__global__ __launch_bounds__(NT) void k_steps4(
    const float* __restrict__ L0T, const float* __restrict__ qc,
    const float* __restrict__ users, const float* __restrict__ servers,
    const uint32_t* __restrict__ connT, const float* __restrict__ fd_onehot,
    const float* __restrict__ W_us, const float* __restrict__ fd_alpha,
    const float* __restrict__ fd_beta, const float* __restrict__ score_bias,
    unsigned long long* __restrict__ propA, unsigned long long* __restrict__ propB,
    float* __restrict__ out) {
  __shared__ float redM[SPB][NT];
  __shared__ int redA[SPB][NT];
  __shared__ unsigned keyEnc4[4][NU];
  __shared__ unsigned srvMin4[4][NU];
  __shared__ float lsum4[4][NU];
  __shared__ unsigned fdSh4[4][NU];
  __shared__ float4 capS4[SPB];
  __shared__ float4 crS4[SPB];
  __shared__ float4 minv4[SPB];
  __shared__ int fidS[SPB];
  __shared__ float pM[SPB][4];
  __shared__ int pA[SPB][4];
  __shared__ float pS[SPB][4];
  __shared__ float wredL[16];
  __shared__ int anyL[4];

  const int blk = blockIdx.x;
  // XCD-clustered bijection: batch b on XCD residues {2b, 2b+1}
  const int b = (blk & 7) >> 1;
  const int g = ((blk >> 3) << 1) | (blk & 1);
  const int tid = threadIdx.x;
  const int wv = tid >> 6, ln64 = tid & 63;
  const int bs0 = b * NS + g * SPB;
  const int bank = tid & 3;
  const int sW = wv >> 2, part = wv & 3;   // wave->server/quarter reduction mapping

  const float a_ = fd_alpha[0], be_ = fd_beta[0];
  const float t0 = tanhf(be_), t1 = tanhf(a_ + be_);
  const float sb = score_bias[0];
  const float w0 = W_us[0], w1 = W_us[1], w2 = W_us[2];

  if (tid < SPB) {
    int srow = bs0 + tid;
    int f = 0;
    for (int ff = 0; ff < NF; ++ff)
      if (fd_onehot[srow * NF + ff] > 0.5f) { f = ff; break; }
    fidS[tid] = f;
    float4 ic = make_float4(servers[srow * 8 + 3], servers[srow * 8 + 4],
                            servers[srow * 8 + 5], servers[srow * 8 + 6]);
    capS4[tid] = ic;
    float4 mv = make_float4(fmaxf(ic.x, 1e-6f), fmaxf(ic.y, 1e-6f),
                            fmaxf(ic.z, 1e-6f), fmaxf(ic.w, 1e-6f));
    minv4[tid] = mv;
    crS4[tid] = make_float4(ic.x / mv.x, ic.y / mv.y, ic.z / mv.z, ic.w / mv.w);
  }

  // per-thread user state: user u == tid of batch b
  const int gu = b * NU + tid;
  float4 q4 = *(const float4*)(qc + gu * 4);
  float2 nA = *(const float2*)(users + gu * 8 + 2);
  float2 nB2 = *(const float2*)(users + gu * 8 + 4);
  const float nax = nA.x, nay = nA.y, nbx = nB2.x, nby = nB2.y;
  float L0r[SPB];
  uint32_t upk = 0;                 // bits 0-15 fdmask, bits 16-17 rc
  float usv = w1;
  float logpv = 0.f;
  uint32_t cb = 0, ab = 0;          // bit s
  // deferred propB consumption state (tid<256 only meaningful)
  int prevPu = 0, prevSlot = 0;
  bool prevValid = false;
#pragma unroll
  for (int s = 0; s < SPB; ++s) {
    L0r[s] = L0T[(size_t)(bs0 + s) * NU + tid];
    uint32_t word = connT[(bs0 + s) * 32 + (tid >> 5)];
    cb |= ((word >> (tid & 31)) & 1u) << s;
  }
  for (int i = tid; i < 4 * NU; i += NT) {
    (&keyEnc4[0][0])[i] = 0u;
    (&srvMin4[0][0])[i] = 0xFFFFFFFFu;
    (&lsum4[0][0])[i] = 0.f;
    (&fdSh4[0][0])[i] = 0u;
  }
  __syncthreads();

  for (int step = 0; step < 32; ++step) {
    unsigned e = (unsigned)(step + 1);
    // ---- phase A: per-thread logits for own user x 4 servers ----
    float cand[SPB];
#pragma unroll
    for (int s = 0; s < SPB; ++s) {
      float4 c = capS4[s];
      float4 cr = crS4[s];
      int fid = fidS[s];
      bool el = ((cb >> s) & 1u) && !((ab >> s) & 1u) &&
                ((upk & 0x30000u) != 0x30000u) &&
                c.x >= nax && c.y >= nay && c.z >= nbx && c.w >= nby;
      float tt = ((upk >> fid) & 1u) ? t0 : t1;
      float lg = L0r[s] + q4.x * cr.x + q4.y * cr.y + q4.z * cr.z + q4.w * cr.w +
                 sb + tt + usv;
      float cv = el ? lg : NEGV;
      cand[s] = cv;
      redM[s][tid] = cv;
      redA[s][tid] = (cv > NEGV) ? tid : 0x7fffffff;
    }
    __syncthreads();                               // B1
    // wave reduce: wave wv handles server sW, quarter part
    {
      int base = part * 256 + ln64 * 4;
      float m = redM[sW][base]; int a = redA[sW][base];
#pragma unroll
      for (int j = 1; j < 4; ++j) {
        float v = redM[sW][base + j]; int aa = redA[sW][base + j];
        if (v > m || (v == m && aa < a)) { m = v; a = aa; }
      }
      for (int o = 32; o; o >>= 1) {
        float ov = __shfl_xor(m, o); int oa = __shfl_xor(a, o);
        if (ov > m || (ov == m && oa < a)) { m = ov; a = oa; }
      }
      if (ln64 == 0) { pM[sW][part] = m; pA[sW][part] = a; }
    }
    __syncthreads();                               // B2
    // every wave locally combines the 4 partials of its server (same order)
    float bm;
    {
      float m = pM[sW][0]; int a = pA[sW][0];
#pragma unroll
      for (int j = 1; j < 4; ++j) {
        float v = pM[sW][j]; int aa = pA[sW][j];
        if (v > m || (v == m && aa < a)) { m = v; a = aa; }
      }
      bm = m;
      if (part == 0 && ln64 == 0) {
        int au = (a == 0x7fffffff) ? 0 : a;
        unsigned validb = (m > -1e8f) ? VBIT : 0u;
        unsigned pinfo = (unsigned)au | ((unsigned)fidS[sW] << 10) | validb | (e << 15);
        unsigned long long Aw = (unsigned long long)pinfo |
                                ((unsigned long long)__float_as_uint(m) << 32);
        __hip_atomic_store(&propA[(step & 1) * (NB * NS) + bs0 + sW], Aw,
                           __ATOMIC_RELAXED, AGENT);
      }
      // fused lse: read raw cands, exp against bm (same values & add order)
      int base = part * 256 + ln64 * 4;
      float ps = expf(redM[sW][base] - bm) + expf(redM[sW][base + 1] - bm) +
                 expf(redM[sW][base + 2] - bm) + expf(redM[sW][base + 3] - bm);
      for (int o = 32; o; o >>= 1) ps += __shfl_xor(ps, o);
      if (ln64 == 0) pS[sW][part] = ps;
    }
    __syncthreads();                               // B3
    if (tid < SPB) {
      float ps = pS[tid][0] + pS[tid][1] + pS[tid][2] + pS[tid][3];
      unsigned long long Bw = (unsigned long long)__float_as_uint(-logf(ps)) |
                              ((unsigned long long)e << 32);
      __hip_atomic_store(&propB[(step & 1) * (NB * NS) + bs0 + tid], Bw,
                         __ATOMIC_RELAXED, AGENT);
    }

    // ---- phase B: single propA poll; deferred prev-step propB consumption ----
    {
      int par = (step & 1) * (NB * NS) + b * NS;
      unsigned pi = 0;
      unsigned encv = 0;
      int pu = 0;
      if (tid < 256) {
        unsigned long long Aw = __hip_atomic_load(&propA[par + tid], __ATOMIC_RELAXED, AGENT);
        if ((((unsigned)Aw >> 15) & 63u) != e) {
          int iters = 0;
          do {
            __builtin_amdgcn_s_sleep(1);
            Aw = __hip_atomic_load(&propA[par + tid], __ATOMIC_RELAXED, AGENT);
            if (++iters > SPINCAP) break;
          } while ((((unsigned)Aw >> 15) & 63u) != e);
        }
        pi = (unsigned)Aw;
        pu = pi & 1023;
        // deferred: add prev step's lsum contribution (propB long since visible)
        if (prevValid) {
          unsigned long long Bw = __hip_atomic_load(&propB[prevSlot], __ATOMIC_RELAXED, AGENT);
          if ((unsigned)(Bw >> 32) != (unsigned)step) {   // prev epoch == step
            int iters = 0;
            do {
              __builtin_amdgcn_s_sleep(1);
              Bw = __hip_atomic_load(&propB[prevSlot], __ATOMIC_RELAXED, AGENT);
              if (++iters > SPINCAP) break;
            } while ((unsigned)(Bw >> 32) != (unsigned)step);
          }
          atomicAdd(&lsum4[bank][prevPu], __uint_as_float((unsigned)Bw));
        }
        prevValid = (pi & VBIT) != 0;
        prevPu = pu;
        prevSlot = par + tid;
        if (pi & VBIT) {
          unsigned vb = (unsigned)(Aw >> 32);
          encv = (vb & 0x80000000u) ? ~vb : (vb | 0x80000000u);
          atomicMax(&keyEnc4[bank][pu], encv);     // phase 1: max only
        }
      }
      unsigned long long mm = __ballot((pi & VBIT) != 0);
      if (wv < 4 && ln64 == 0) anyL[wv] = (mm != 0ull) ? 1 : 0;
      __syncthreads();                              // B4: all atomicMax+prevAdd done
      if (!(anyL[0] | anyL[1] | anyL[2] | anyL[3])) break;  // batch frozen forever
      if ((tid < 256) && (pi & VBIT)) {
        if (keyEnc4[bank][pu] == encv)              // phase 2: bank max is final
          atomicMin(&srvMin4[bank][pu], (unsigned)tid);
        atomicOr(&fdSh4[bank][pu], 1u << ((pi >> 10) & 15));
      }
      __syncthreads();                              // B5: all min/or complete
      {
        int u = tid;
        unsigned k0 = keyEnc4[0][u], k1 = keyEnc4[1][u];
        unsigned k2 = keyEnc4[2][u], k3 = keyEnc4[3][u];
        unsigned gmax = max(max(k0, k1), max(k2, k3));
        if (gmax) {
          unsigned win = 0xFFFFFFFFu;
          if (k0 == gmax) win = min(win, srvMin4[0][u]);
          if (k1 == gmax) win = min(win, srvMin4[1][u]);
          if (k2 == gmax) win = min(win, srvMin4[2][u]);
          if (k3 == gmax) win = min(win, srvMin4[3][u]);
          float ls = lsum4[0][u] + lsum4[1][u] + lsum4[2][u] + lsum4[3][u];
          unsigned fda = fdSh4[0][u] | fdSh4[1][u] | fdSh4[2][u] | fdSh4[3][u];
          keyEnc4[0][u] = 0u; keyEnc4[1][u] = 0u; keyEnc4[2][u] = 0u; keyEnc4[3][u] = 0u;
          srvMin4[0][u] = 0xFFFFFFFFu; srvMin4[1][u] = 0xFFFFFFFFu;
          srvMin4[2][u] = 0xFFFFFFFFu; srvMin4[3][u] = 0xFFFFFFFFu;
          lsum4[0][u] = 0.f; lsum4[1][u] = 0.f; lsum4[2][u] = 0.f; lsum4[3][u] = 0.f;
          fdSh4[0][u] = 0u; fdSh4[1][u] = 0u; fdSh4[2][u] = 0u; fdSh4[3][u] = 0u;
          logpv += ls;                               // lsum lags one step; totals identical
          uint32_t pk = upk;
          int r = (int)((pk >> 16) & 3) + 1;
          upk = ((pk | fda) & 0xFFFFu) | ((uint32_t)r << 16);
          float rf = (float)r;
          usv = w0 * (rf / 3.0f) + w1 * (fmaxf(3.0f - rf, 0.f) / 3.0f) +
                ((r == 2) ? w2 : 0.f);
          if ((int)(win >> 2) == g) {
            int sl = win & 3;
            ab |= 1u << sl;
            float4 c = capS4[sl];        // unique (server,step) winner -> no race
            float4 nc = make_float4(fmaxf(c.x - nax, 0.f), fmaxf(c.y - nay, 0.f),
                                    fmaxf(c.z - nbx, 0.f), fmaxf(c.w - nby, 0.f));
            capS4[sl] = nc;
            float4 mv = minv4[sl];
            crS4[sl] = make_float4(nc.x / mv.x, nc.y / mv.y, nc.z / mv.z, nc.w / mv.w);
          }
        }
      }
      __syncthreads();                              // B6
    }
  }

  // ---- final flush: last step's deferred lsum + any unconsumed residue ----
  if ((tid < 256) && prevValid) {
    unsigned long long Bw = __hip_atomic_load(&propB[prevSlot], __ATOMIC_RELAXED, AGENT);
    // epoch is guaranteed current (produced by this block's batch before loop exit)
    atomicAdd(&lsum4[bank][prevPu], __uint_as_float((unsigned)Bw));
  }
  __syncthreads();
  logpv += lsum4[0][tid] + lsum4[1][tid] + lsum4[2][tid] + lsum4[3][tid];

  // ---- fused outputs: alloc expansion + cap + logp ----
  {
    float4 o;
    o.x = (ab & 1u) ? 1.f : 0.f;
    o.y = ((ab >> 1) & 1u) ? 1.f : 0.f;
    o.z = ((ab >> 2) & 1u) ? 1.f : 0.f;
    o.w = ((ab >> 3) & 1u) ? 1.f : 0.f;
    *(float4*)(out + 4 + (size_t)(b * NU + tid) * NS + g * 4) = o;
  }
  if (tid < SPB)
    *(float4*)(out + 4 + (size_t)NB * NU * NS + (size_t)(bs0 + tid) * 4) = capS4[tid];
  if (g == 0) {
    float a2 = logpv;
    for (int o = 32; o; o >>= 1) a2 += __shfl_xor(a2, o);
    if (ln64 == 0) wredL[wv] = a2;
    __syncthreads();
    if (tid == 0) {
      float s = 0.f;
#pragma unroll
      for (int i = 0; i < 16; ++i) s += wredL[i];
      out[b] = s;
    }
  }
}

extern "C" void kernel_launch(void* const* d_in, const int* in_sizes, int n_in,
                              void* d_out, int out_size, void* d_ws, size_t ws_size,
                              hipStream_t stream) {
  const float* user_enc = (const float*)d_in[0];
  const float* server_enc = (const float*)d_in[1];
  const float* users = (const float*)d_in[2];
  const float* servers = (const float*)d_in[3];
  const uint8_t* connect = (const uint8_t*)d_in[4];
  const float* fd_onehot = (const float*)d_in[5];
  const float* W_state = (const float*)d_in[6];
  const float* b_state = (const float*)d_in[7];
  const float* W_q = (const float*)d_in[8];
  const float* W_k = (const float*)d_in[9];
  const float* W_us = (const float*)d_in[10];
  const float* fd_alpha = (const float*)d_in[11];
  const float* fd_beta = (const float*)d_in[12];
  const float* score_bias = (const float*)d_in[13];

  char* ws = (char*)d_ws;
  size_t off = 0;
  auto take = [&](size_t bytes) -> void* {
    size_t cur = off;
    off = (off + bytes + 255) & ~(size_t)255;
    return (void*)(ws + cur);
  };
  unsigned long long* propA = (unsigned long long*)take((size_t)2 * NB * NS * 8);  // 16KB
  unsigned long long* propB = (unsigned long long*)take((size_t)2 * NB * NS * 8);  // 16KB (contiguous)
  float* q = (float*)take((size_t)NB * NU * ND * 4);
  float* kb = (float*)take((size_t)NB * NS * ND * 4);
  float* L0T = (float*)take((size_t)NB * NS * NU * 4);
  float* qc = (float*)take((size_t)NB * NU * 4 * 4);
  float* WS_K = (float*)take((size_t)ND * 4 * 4);
  uint32_t* connT = (uint32_t*)take((size_t)NB * NS * 32 * 4);
  float* outp = (float*)d_out;

  // 3 dispatches total
  k_pre1<<<450, 256, 0, stream>>>(connect, W_state, W_k, user_enc, server_enc, b_state,
                                  W_q, connT, WS_K, q, kb, (float4*)propA);
  k_pre2<<<1280, 256, 0, stream>>>(q, WS_K, qc, kb, L0T);
  k_steps4<<<NB * NGRP, NT, 0, stream>>>(
      L0T, qc, users, servers, connT, fd_onehot, W_us, fd_alpha, fd_beta, score_bias,
      propA, propB, outp);
}